// Round 1
// baseline (1346.009 us; speedup 1.0000x reference)
//
#include <hip/hip_runtime.h>
#include <cstdint>
#include <cstddef>

// ---------------------------------------------------------------------------
// Qwen3VL-with-experts fused forward, bf16 MFMA implementation.
// B=2, S=(1024,256,64)->1344, H=16, KV=8, D=128, hid=(2048,1024,1024),
// ffn=(8192,4096,4096). All GEMM dims are multiples of 128 -> no bounds checks.
// ---------------------------------------------------------------------------

using u16 = unsigned short;
typedef __attribute__((ext_vector_type(4))) float  f32x4;
typedef __attribute__((ext_vector_type(4))) u16    u16x4;
typedef __attribute__((ext_vector_type(8))) u16    u16x8;
typedef __attribute__((ext_vector_type(8))) short  s16x8;

__device__ __forceinline__ u16 f2bf(float f) {
  unsigned u = __builtin_bit_cast(unsigned, f);
  u = (u + 0x7FFF + ((u >> 16) & 1)) >> 16;
  return (u16)u;
}
__device__ __forceinline__ float bf2f(u16 h) {
  unsigned u = ((unsigned)h) << 16;
  return __builtin_bit_cast(float, u);
}
__device__ __forceinline__ f32x4 mfma16(s16x8 a, s16x8 b, f32x4 c) {
  return __builtin_amdgcn_mfma_f32_16x16x32_bf16(a, b, c, 0, 0, 0);
}
__device__ __forceinline__ void gl_lds16(const u16* g, u16* l) {
  __builtin_amdgcn_global_load_lds(
      (const __attribute__((address_space(1))) unsigned int*)g,
      (__attribute__((address_space(3))) unsigned int*)l, 16, 0, 0);
}

// ---------------- workspace layout (bytes) ----------------
// all sizes multiples of 1024
static constexpr size_t WB_OFF   = 0;                       // bf16 weights  201326592
static constexpr size_t H1_OFF   = WB_OFF   + 201326592;    // 9699328
static constexpr size_t H2_OFF   = H1_OFF   + 9699328;      // 9699328
static constexpr size_t QPRE_OFF = H2_OFF   + 9699328;      // 11010048
static constexpr size_t KPRE_OFF = QPRE_OFF + 11010048;     // 5505024
static constexpr size_t VPRE_OFF = KPRE_OFF + 5505024;      // 5505024
static constexpr size_t QB_OFF   = VPRE_OFF + 5505024;      // 11010048
static constexpr size_t KB_OFF   = QB_OFF   + 11010048;     // 5505024
static constexpr size_t VT_OFF   = KB_OFF   + 5505024;      // 5505024
static constexpr size_t ATTO_OFF = VT_OFF   + 5505024;      // 11010048
static constexpr size_t G_OFF    = ATTO_OFF + 11010048;     // 38797312
static constexpr size_t U_OFF    = G_OFF    + 38797312;     // 38797312
static constexpr size_t WS_NEED  = U_OFF    + 38797312;     // 353370112

// ---------------- weight cast: 21 matrices, one launch ----------------
struct CastTab { const float* src[21]; int pre[22]; };

__global__ __launch_bounds__(256) void cast_weights(CastTab tab, u16* __restrict__ dst) {
  int c = blockIdx.x;            // chunk of 32768 elems
  int a = 0;
  while (c >= tab.pre[a + 1]) a++;
  const f32x4* s = (const f32x4*)(tab.src[a] + ((size_t)(c - tab.pre[a]) << 15));
  u16x4* d = (u16x4*)(dst + ((size_t)c << 15));
  int t = threadIdx.x;
  for (int i = t; i < 8192; i += 256) {
    f32x4 v = s[i];
    u16x4 o; o[0] = f2bf(v[0]); o[1] = f2bf(v[1]); o[2] = f2bf(v[2]); o[3] = f2bf(v[3]);
    d[i] = o;
  }
}

// ---------------- RMSNorm (f32 in) -> bf16 out ----------------
__global__ __launch_bounds__(256) void rmsnorm_cast(
    const float* __restrict__ x, const float* __restrict__ w,
    u16* __restrict__ out, int hid) {
  int row = blockIdx.x;
  const f32x4* xr = (const f32x4*)(x + (size_t)row * hid);
  const f32x4* wr = (const f32x4*)w;
  int n4 = hid >> 2;
  int t = threadIdx.x;
  float ss = 0.f;
  for (int i = t; i < n4; i += 256) {
    f32x4 v = xr[i];
    ss += v[0] * v[0] + v[1] * v[1] + v[2] * v[2] + v[3] * v[3];
  }
#pragma unroll
  for (int m = 1; m < 64; m <<= 1) ss += __shfl_xor(ss, m);
  __shared__ float part[4];
  if ((t & 63) == 0) part[t >> 6] = ss;
  __syncthreads();
  float tot = part[0] + part[1] + part[2] + part[3];
  float rs = rsqrtf(tot / (float)hid + 1e-6f);
  u16x4* orow = (u16x4*)(out + (size_t)row * hid);
  for (int i = t; i < n4; i += 256) {
    f32x4 v = xr[i];
    f32x4 g = wr[i];
    u16x4 o;
    o[0] = f2bf(v[0] * rs * g[0]); o[1] = f2bf(v[1] * rs * g[1]);
    o[2] = f2bf(v[2] * rs * g[2]); o[3] = f2bf(v[3] * rs * g[3]);
    orow[i] = o;
  }
}

// ---------------- GEMM: C(MxN) = A(MxK) * B(N,K)^T, bf16 in, m97 structure ----
// A row gather: grow = (r>>logSe)*bstride + (r & ((1<<logSe)-1)) + rowoff
// (contiguous A: logSe=log2(M), bstride=0, rowoff=0)
// RESID: 0 none; 1 add R[] (f32); 2 add C[] in place (f32)
// OUTBF: 1 -> bf16 C; 0 -> f32 C
template <int RESID, int OUTBF>
__global__ __launch_bounds__(256) void gemm_bt(
    const u16* __restrict__ A, int logSe, int bstride, int rowoff,
    const u16* __restrict__ Bw, int K, int N,
    void* __restrict__ C, const float* __restrict__ R) {
  __shared__ u16 As[128 * 64];
  __shared__ u16 Bs[128 * 64];
  const int t = threadIdx.x;
  const int nt = blockIdx.x, mt = blockIdx.y;
  const int w = t >> 6, l = t & 63;
  const int wr = (w >> 1) * 64, wc = (w & 1) * 64;
  const int l15 = l & 15, lg = l >> 4;
  f32x4 acc[4][4];
#pragma unroll
  for (int i = 0; i < 4; i++)
#pragma unroll
    for (int j = 0; j < 4; j++) acc[i][j] = (f32x4){0.f, 0.f, 0.f, 0.f};

  const int sr = t >> 3, su0 = t & 7;
  const int mask_se = (1 << logSe) - 1;

  for (int kt = 0; kt < K; kt += 64) {
    __syncthreads();
    // stage A (16KB) : 4 issues x 256 lanes x 16B, swizzled global source
#pragma unroll
    for (int i = 0; i < 4; i++) {
      int row = i * 32 + sr;
      int gr = mt * 128 + row;
      int grow = ((gr >> logSe) * bstride) + (gr & mask_se) + rowoff;
      int su = su0 ^ (row & 7);
      gl_lds16(A + (size_t)grow * K + kt + su * 8, &As[row * 64 + su0 * 8]);
    }
#pragma unroll
    for (int i = 0; i < 4; i++) {
      int row = i * 32 + sr;
      int gc = nt * 128 + row;
      int su = su0 ^ (row & 7);
      gl_lds16(Bw + (size_t)gc * K + kt + su * 8, &Bs[row * 64 + su0 * 8]);
    }
    __syncthreads();

    s16x8 af[2][4], bfr[2][4];
#pragma unroll
    for (int mi = 0; mi < 4; mi++) {
      int row = wr + mi * 16 + l15;
#pragma unroll
      for (int ks = 0; ks < 2; ks++) {
        int u = ks * 4 + lg;
        af[ks][mi] = *(const s16x8*)&As[row * 64 + (u ^ (row & 7)) * 8];
      }
    }
#pragma unroll
    for (int ni = 0; ni < 4; ni++) {
      int row = wc + ni * 16 + l15;
#pragma unroll
      for (int ks = 0; ks < 2; ks++) {
        int u = ks * 4 + lg;
        bfr[ks][ni] = *(const s16x8*)&Bs[row * 64 + (u ^ (row & 7)) * 8];
      }
    }
#pragma unroll
    for (int ks = 0; ks < 2; ks++)
#pragma unroll
      for (int mi = 0; mi < 4; mi++)
#pragma unroll
        for (int ni = 0; ni < 4; ni++)
          acc[mi][ni] = mfma16(af[ks][mi], bfr[ks][ni], acc[mi][ni]);
  }

#pragma unroll
  for (int mi = 0; mi < 4; mi++) {
#pragma unroll
    for (int r = 0; r < 4; r++) {
      int crow = mt * 128 + wr + mi * 16 + lg * 4 + r;
      size_t rb = (size_t)crow * N;
#pragma unroll
      for (int ni = 0; ni < 4; ni++) {
        int col = nt * 128 + wc + ni * 16 + l15;
        float v = acc[mi][ni][r];
        if (RESID == 1) v += R[rb + col];
        if (RESID == 2) v += ((const float*)C)[rb + col];
        if (OUTBF) ((u16*)C)[rb + col] = f2bf(v);
        else       ((float*)C)[rb + col] = v;
      }
    }
  }
}

// ---------------- QK norm + RoPE + scatter ----------------
__global__ __launch_bounds__(256) void qk_rope(
    const u16* __restrict__ qpre, const u16* __restrict__ kpre,
    const float* __restrict__ qn0, const float* __restrict__ qn1, const float* __restrict__ qn2,
    const float* __restrict__ kn0, const float* __restrict__ kn1, const float* __restrict__ kn2,
    const int* __restrict__ pos, u16* __restrict__ Q, u16* __restrict__ K) {
  int tk = blockIdx.x;
  int b = tk / 1344, sg = tk % 1344;
  int w = threadIdx.x >> 6, l = threadIdx.x & 63;
  int hr = blockIdx.y * 4 + w;           // 0..15 q heads, 16..23 k heads
  int e, off, Se;
  if (sg < 1024)      { e = 0; off = 0;    Se = 1024; }
  else if (sg < 1280) { e = 1; off = 1024; Se = 256;  }
  else                { e = 2; off = 1280; Se = 64;   }
  int r = b * Se + (sg - off);
  const u16* src; const float* nw; u16* dst;
  if (hr < 16) {
    size_t qpo = (e == 0) ? 0 : (e == 1) ? 4194304 : 5242880;
    src = qpre + qpo + (size_t)r * 2048 + hr * 128;
    nw = (e == 0) ? qn0 : (e == 1) ? qn1 : qn2;
    dst = Q + ((size_t)(b * 16 + hr) * 1344 + sg) * 128;
  } else {
    int kh = hr - 16;
    size_t kpo = (e == 0) ? 0 : (e == 1) ? 2097152 : 2621440;
    src = kpre + kpo + (size_t)r * 1024 + kh * 128;
    nw = (e == 0) ? kn0 : (e == 1) ? kn1 : kn2;
    dst = K + ((size_t)(b * 8 + kh) * 1344 + sg) * 128;
  }
  float x0v = bf2f(src[l]), x1v = bf2f(src[l + 64]);
  float ss = x0v * x0v + x1v * x1v;
#pragma unroll
  for (int m = 1; m < 64; m <<= 1) ss += __shfl_xor(ss, m);
  float rs = rsqrtf(ss * (1.f / 128.f) + 1e-6f);
  float y0 = x0v * rs * nw[l], y1 = x1v * rs * nw[l + 64];
  float p = (float)pos[b * 1344 + sg];
  float inv = exp2f(-(float)l * 0.3114307588956902f);  // log2(1e6)/64
  float th = p * inv;
  float c = cosf(th), s = sinf(th);
  dst[l]      = f2bf(y0 * c - y1 * s);
  dst[l + 64] = f2bf(y1 * c + y0 * s);
}

// ---------------- V transpose: (tokens, kvh*128+d) -> (B,KV,D,S) ----------------
__global__ __launch_bounds__(256) void v_trans(const u16* __restrict__ vpre, u16* __restrict__ Vt) {
  __shared__ u16 tile[64][72];
  int st = blockIdx.x;
  int b = st / 21, s0 = (st % 21) * 64;
  int kvh = blockIdx.y >> 1, dh = (blockIdx.y & 1) * 64;
  int t = threadIdx.x;
  int sl = t >> 2, d0 = (t & 3) * 16;
  int sg = s0 + sl;
  int e, off, Se;
  if (sg < 1024)      { e = 0; off = 0;    Se = 1024; }
  else if (sg < 1280) { e = 1; off = 1024; Se = 256;  }
  else                { e = 2; off = 1280; Se = 64;   }
  int r = b * Se + (sg - off);
  size_t vpo = (e == 0) ? 0 : (e == 1) ? 2097152 : 2621440;
  const u16* src = vpre + vpo + (size_t)r * 1024 + kvh * 128 + dh + d0;
  u16x8 a = *(const u16x8*)src;
  u16x8 bb = *(const u16x8*)(src + 8);
#pragma unroll
  for (int j = 0; j < 8; j++) { tile[sl][d0 + j] = a[j]; tile[sl][d0 + 8 + j] = bb[j]; }
  __syncthreads();
  int dl = t >> 2, sb = (t & 3) * 16;
  u16* dst = Vt + ((size_t)(b * 8 + kvh) * 128 + dh + dl) * 1344 + s0 + sb;
  u16x8 o0, o1;
#pragma unroll
  for (int j = 0; j < 8; j++) { o0[j] = tile[sb + j][dl]; o1[j] = tile[sb + 8 + j][dl]; }
  *(u16x8*)dst = o0;
  *(u16x8*)(dst + 8) = o1;
}

// ---------------- Flash attention: Q(B,H,S,D), K(B,KV,S,D), Vt(B,KV,D,S) ------
__global__ __launch_bounds__(256, 2) void attn(
    const u16* __restrict__ Q, const u16* __restrict__ K, const u16* __restrict__ Vt,
    const float* __restrict__ mask, u16* __restrict__ attO) {
  constexpr int S = 1344;
  __shared__ u16 Qs[64 * 128];
  __shared__ u16 Ks[64 * 128];
  __shared__ u16 Vts[128 * 64];
  __shared__ u16 Ps[4][16 * 64];
  int bh = blockIdx.y;
  int b = bh >> 4, h = bh & 15, kvh = h >> 1;
  int q0 = blockIdx.x * 64;
  int t = threadIdx.x, w = t >> 6, l = t & 63;
  const int l15 = l & 15, lg = l >> 4;
  const u16* Qg = Q + ((size_t)(b * 16 + h) * S + q0) * 128;
  const u16* Kg = K + ((size_t)(b * 8 + kvh) * S) * 128;
  const u16* Vg = Vt + ((size_t)(b * 8 + kvh) * 128) * S;

  // stage Q tile (64x128)
  {
    int unit = t & 15, r16 = t >> 4;
#pragma unroll
    for (int i = 0; i < 4; i++) {
      int row = i * 16 + r16;
      int su = (unit & 8) | ((unit & 7) ^ (row & 7));
      gl_lds16(Qg + (size_t)row * 128 + su * 8, &Qs[row * 128 + unit * 8]);
    }
  }
  __syncthreads();
  s16x8 qf[4];
  {
    int qrow = w * 16 + l15;
#pragma unroll
    for (int ks = 0; ks < 4; ks++) {
      int u = ks * 4 + lg;
      int su = (u & 8) | ((u & 7) ^ (qrow & 7));
      qf[ks] = *(const s16x8*)&Qs[qrow * 128 + su * 8];
    }
  }

  float mrow[4] = {-3e38f, -3e38f, -3e38f, -3e38f};
  float lrow[4] = {0.f, 0.f, 0.f, 0.f};
  f32x4 of[8];
#pragma unroll
  for (int d = 0; d < 8; d++) of[d] = (f32x4){0.f, 0.f, 0.f, 0.f};
  const float scale = 0.08838834764831845f;

  for (int kt = 0; kt < 21; ++kt) {
    int k0 = kt * 64;
    __syncthreads();
    {
      int unit = t & 15, r16 = t >> 4;
#pragma unroll
      for (int i = 0; i < 4; i++) {
        int row = i * 16 + r16;
        int su = (unit & 8) | ((unit & 7) ^ (row & 7));
        gl_lds16(Kg + (size_t)(k0 + row) * 128 + su * 8, &Ks[row * 128 + unit * 8]);
      }
      int u8 = t & 7, r32 = t >> 3;
#pragma unroll
      for (int i = 0; i < 4; i++) {
        int row = i * 32 + r32;
        int su = u8 ^ (row & 7);
        gl_lds16(Vg + (size_t)row * S + k0 + su * 8, &Vts[row * 64 + u8 * 8]);
      }
    }
    __syncthreads();

    // S = Q K^T
    f32x4 sf[4];
#pragma unroll
    for (int cb = 0; cb < 4; cb++) {
      f32x4 a = (f32x4){0.f, 0.f, 0.f, 0.f};
      int krow = cb * 16 + l15;
#pragma unroll
      for (int ks = 0; ks < 4; ks++) {
        int u = ks * 4 + lg;
        int su = (u & 8) | ((u & 7) ^ (krow & 7));
        s16x8 kf = *(const s16x8*)&Ks[krow * 128 + su * 8];
        a = mfma16(qf[ks], kf, a);
      }
      sf[cb] = a;
    }

    // scale + mask, online softmax
    float pv[4][4], tmax[4];
    int qg0 = q0 + w * 16 + lg * 4;
#pragma unroll
    for (int r = 0; r < 4; r++) {
      const float* mp = mask + ((size_t)(b * S + qg0 + r)) * S + k0 + l15;
      float v0 = sf[0][r] * scale + mp[0];
      float v1 = sf[1][r] * scale + mp[16];
      float v2 = sf[2][r] * scale + mp[32];
      float v3 = sf[3][r] * scale + mp[48];
      pv[0][r] = v0; pv[1][r] = v1; pv[2][r] = v2; pv[3][r] = v3;
      tmax[r] = fmaxf(fmaxf(v0, v1), fmaxf(v2, v3));
    }
#pragma unroll
    for (int m = 1; m < 16; m <<= 1)
#pragma unroll
      for (int r = 0; r < 4; r++) tmax[r] = fmaxf(tmax[r], __shfl_xor(tmax[r], m));

    float fr[4];
#pragma unroll
    for (int r = 0; r < 4; r++) {
      float mnew = fmaxf(mrow[r], tmax[r]);
      fr[r] = __expf(mrow[r] - mnew);
      mrow[r] = mnew;
      float rs = 0.f;
#pragma unroll
      for (int cb = 0; cb < 4; cb++) { pv[cb][r] = __expf(pv[cb][r] - mnew); rs += pv[cb][r]; }
#pragma unroll
      for (int m = 1; m < 16; m <<= 1) rs += __shfl_xor(rs, m);
      lrow[r] = lrow[r] * fr[r] + rs;
    }
#pragma unroll
    for (int d = 0; d < 8; d++)
#pragma unroll
      for (int r = 0; r < 4; r++) of[d][r] *= fr[r];

    // P -> LDS (per-wave, swizzled)
#pragma unroll
    for (int cb = 0; cb < 4; cb++)
#pragma unroll
      for (int r = 0; r < 4; r++) {
        int prow = lg * 4 + r;
        int col = cb * 16 + l15;
        int su = (col >> 3) ^ (prow & 7);
        Ps[w][prow * 64 + su * 8 + (col & 7)] = f2bf(pv[cb][r]);
      }
    __syncthreads();

    // O += P V
    s16x8 pa[2];
#pragma unroll
    for (int ks = 0; ks < 2; ks++) {
      int prow = l15;
      int u = ks * 4 + lg;
      pa[ks] = *(const s16x8*)&Ps[w][prow * 64 + (u ^ (prow & 7)) * 8];
    }
#pragma unroll
    for (int d = 0; d < 8; d++) {
      int vrow = d * 16 + l15;
#pragma unroll
      for (int ks = 0; ks < 2; ks++) {
        int u = ks * 4 + lg;
        s16x8 vf = *(const s16x8*)&Vts[vrow * 64 + (u ^ (vrow & 7)) * 8];
        of[d] = mfma16(pa[ks], vf, of[d]);
      }
    }
  }

  // epilogue: O/l -> attO (B,S,H*D)
#pragma unroll
  for (int r = 0; r < 4; r++) {
    float il = 1.f / lrow[r];
    int sg = q0 + w * 16 + lg * 4 + r;
    u16* orow = attO + ((size_t)(b * S + sg)) * 2048 + h * 128;
#pragma unroll
    for (int d = 0; d < 8; d++) orow[d * 16 + l15] = f2bf(of[d][r] * il);
  }
}

// ---------------- silu(g)*u (bf16, in-place into g) ----------------
__global__ __launch_bounds__(256) void silu_mul(
    const u16* __restrict__ g, const u16* __restrict__ u, u16* __restrict__ m, long n8) {
  long i = (long)blockIdx.x * 256 + threadIdx.x;
  if (i >= n8) return;
  u16x8 gv = ((const u16x8*)g)[i];
  u16x8 uv = ((const u16x8*)u)[i];
  u16x8 o;
#pragma unroll
  for (int j = 0; j < 8; j++) {
    float gf = bf2f(gv[j]), uf = bf2f(uv[j]);
    float s = gf / (1.f + __expf(-gf));
    o[j] = f2bf(s * uf);
  }
  ((u16x8*)m)[i] = o;
}

// ---------------------------------------------------------------------------
extern "C" void kernel_launch(void* const* d_in, const int* in_sizes, int n_in,
                              void* d_out, int out_size, void* d_ws, size_t ws_size,
                              hipStream_t stream) {
  if (ws_size < WS_NEED) return;  // fail loudly via validation rather than corrupt

  const float* x[3] = {(const float*)d_in[0], (const float*)d_in[1], (const float*)d_in[2]};
  const float* mask = (const float*)d_in[3];
  const int* pos = (const int*)d_in[4];
  auto W = [&](int e, int k) -> const float* { return (const float*)d_in[5 + e * 11 + k]; };
  // k: 0 ln1, 1 ln2, 2 wq, 3 wk, 4 wv, 5 wo, 6 qn, 7 kn, 8 wg, 9 wu, 10 wd

  char* ws = (char*)d_ws;
  u16* wbf  = (u16*)(ws + WB_OFF);
  u16* h1   = (u16*)(ws + H1_OFF);
  u16* h2   = (u16*)(ws + H2_OFF);
  u16* qpre = (u16*)(ws + QPRE_OFF);
  u16* kpre = (u16*)(ws + KPRE_OFF);
  u16* vpre = (u16*)(ws + VPRE_OFF);
  u16* Qb   = (u16*)(ws + QB_OFF);
  u16* Kb   = (u16*)(ws + KB_OFF);
  u16* Vtb  = (u16*)(ws + VT_OFF);
  u16* attO = (u16*)(ws + ATTO_OFF);
  u16* g    = (u16*)(ws + G_OFF);
  u16* u    = (u16*)(ws + U_OFF);
  float* dout = (float*)d_out;

  const int hid[3] = {2048, 1024, 1024}, ffn[3] = {8192, 4096, 4096};
  const int M[3] = {2048, 512, 128};
  const int logM[3] = {11, 9, 7}, logSe[3] = {10, 8, 6}, eoff[3] = {0, 1024, 1280};
  const size_t h1o[3]  = {0, 4194304, 4718592};       // also d_out offsets
  const size_t qpo[3]  = {0, 4194304, 5242880};
  const size_t kpo[3]  = {0, 2097152, 2621440};
  const size_t go[3]   = {0, 16777216, 18874368};

  // weight table + bf16 offsets (order: wq,wk,wv,wo,wg,wu,wd per expert)
  size_t woff[3][7];
  CastTab tab;
  {
    size_t cum = 0; int cc = 0, ci = 0;
    for (int e = 0; e < 3; e++) {
      const int kidx[7] = {2, 3, 4, 5, 8, 9, 10};
      const size_t sz[7] = {(size_t)2048 * hid[e], (size_t)1024 * hid[e], (size_t)1024 * hid[e],
                            (size_t)2048 * hid[e], (size_t)ffn[e] * hid[e],
                            (size_t)ffn[e] * hid[e], (size_t)ffn[e] * hid[e]};
      for (int j = 0; j < 7; j++) {
        woff[e][j] = cum;
        tab.src[ci] = W(e, kidx[j]);
        tab.pre[ci] = cc;
        cum += sz[j];
        cc += (int)(sz[j] >> 15);
        ci++;
      }
    }
    tab.pre[21] = cc;  // 3072 chunks
  }

  // 1. weights -> bf16
  cast_weights<<<dim3(3072), dim3(256), 0, stream>>>(tab, wbf);

  // 2. RMSNorm(ln1) -> h1
  for (int e = 0; e < 3; e++)
    rmsnorm_cast<<<dim3(M[e]), dim3(256), 0, stream>>>(x[e], W(e, 0), h1 + h1o[e], hid[e]);

  // 3. QKV projections
  for (int e = 0; e < 3; e++) {
    gemm_bt<0, 1><<<dim3(16, M[e] / 128), dim3(256), 0, stream>>>(
        h1 + h1o[e], logM[e], 0, 0, wbf + woff[e][0], hid[e], 2048, qpre + qpo[e], nullptr);
    gemm_bt<0, 1><<<dim3(8, M[e] / 128), dim3(256), 0, stream>>>(
        h1 + h1o[e], logM[e], 0, 0, wbf + woff[e][1], hid[e], 1024, kpre + kpo[e], nullptr);
    gemm_bt<0, 1><<<dim3(8, M[e] / 128), dim3(256), 0, stream>>>(
        h1 + h1o[e], logM[e], 0, 0, wbf + woff[e][2], hid[e], 1024, vpre + kpo[e], nullptr);
  }

  // 4. q/k norm + rope + scatter; V transpose
  qk_rope<<<dim3(2688, 6), dim3(256), 0, stream>>>(
      qpre, kpre, W(0, 6), W(1, 6), W(2, 6), W(0, 7), W(1, 7), W(2, 7), pos, Qb, Kb);
  v_trans<<<dim3(42, 16), dim3(256), 0, stream>>>(vpre, Vtb);

  // 5. attention
  attn<<<dim3(21, 32), dim3(256), 0, stream>>>(Qb, Kb, Vtb, mask, attO);

  // 6. o = att @ wo^T + x  -> d_out (f32)
  for (int e = 0; e < 3; e++)
    gemm_bt<1, 0><<<dim3(hid[e] / 128, M[e] / 128), dim3(256), 0, stream>>>(
        attO, logSe[e], 1344, eoff[e], wbf + woff[e][3], 2048, hid[e],
        dout + h1o[e], x[e]);

  // 7. RMSNorm(ln2) -> h2
  for (int e = 0; e < 3; e++)
    rmsnorm_cast<<<dim3(M[e]), dim3(256), 0, stream>>>(dout + h1o[e], W(e, 1), h2 + h1o[e], hid[e]);

  // 8. g/u projections
  for (int e = 0; e < 3; e++) {
    gemm_bt<0, 1><<<dim3(ffn[e] / 128, M[e] / 128), dim3(256), 0, stream>>>(
        h2 + h1o[e], logM[e], 0, 0, wbf + woff[e][4], hid[e], ffn[e], g + go[e], nullptr);
    gemm_bt<0, 1><<<dim3(ffn[e] / 128, M[e] / 128), dim3(256), 0, stream>>>(
        h2 + h1o[e], logM[e], 0, 0, wbf + woff[e][5], hid[e], ffn[e], u + go[e], nullptr);
  }

  // 9. m = silu(g)*u (in place into g)
  silu_mul<<<dim3(9472), dim3(256), 0, stream>>>(g, u, g, 2424832L);

  // 10. out += m @ wd^T
  for (int e = 0; e < 3; e++)
    gemm_bt<2, 0><<<dim3(hid[e] / 128, M[e] / 128), dim3(256), 0, stream>>>(
        g + go[e], logM[e], 0, 0, wbf + woff[e][6], ffn[e], hid[e], dout + h1o[e], nullptr);
}

// Round 2
// 814.322 us; speedup vs baseline: 1.6529x; 1.6529x over previous
//
#include <hip/hip_runtime.h>
#include <cstdint>
#include <cstddef>

// ---------------------------------------------------------------------------
// Qwen3VL-with-experts fused forward, bf16 MFMA implementation. Round 2:
// fused QKV + fused G/U GEMMs, split-K (two-pass deterministic reduce) for
// small-grid GEMMs, bijective XCD swizzle on GEMM tiles.
// ---------------------------------------------------------------------------

using u16 = unsigned short;
typedef __attribute__((ext_vector_type(4))) float  f32x4;
typedef __attribute__((ext_vector_type(4))) u16    u16x4;
typedef __attribute__((ext_vector_type(8))) u16    u16x8;
typedef __attribute__((ext_vector_type(8))) short  s16x8;

__device__ __forceinline__ u16 f2bf(float f) {
  unsigned u = __builtin_bit_cast(unsigned, f);
  u = (u + 0x7FFF + ((u >> 16) & 1)) >> 16;
  return (u16)u;
}
__device__ __forceinline__ float bf2f(u16 h) {
  unsigned u = ((unsigned)h) << 16;
  return __builtin_bit_cast(float, u);
}
__device__ __forceinline__ f32x4 mfma16(s16x8 a, s16x8 b, f32x4 c) {
  return __builtin_amdgcn_mfma_f32_16x16x32_bf16(a, b, c, 0, 0, 0);
}
__device__ __forceinline__ void gl_lds16(const u16* g, u16* l) {
  __builtin_amdgcn_global_load_lds(
      (const __attribute__((address_space(1))) unsigned int*)g,
      (__attribute__((address_space(3))) unsigned int*)l, 16, 0, 0);
}

// ---------------- workspace layout (bytes) ----------------
static constexpr size_t WB_OFF   = 0;                       // bf16 weights 201326592
static constexpr size_t H1_OFF   = WB_OFF   + 201326592;    // 9699328
static constexpr size_t H2_OFF   = H1_OFF   + 9699328;      // 9699328
static constexpr size_t QKV_OFF  = H2_OFF   + 9699328;      // 22020096 (2688 x 4096 bf16)
static constexpr size_t QB_OFF   = QKV_OFF  + 22020096;     // 11010048
static constexpr size_t KB_OFF   = QB_OFF   + 11010048;     // 5505024
static constexpr size_t VT_OFF   = KB_OFF   + 5505024;      // 5505024
static constexpr size_t ATTO_OFF = VT_OFF   + 5505024;      // 11010048
static constexpr size_t GU_OFF   = ATTO_OFF + 11010048;     // 77594624 (fused g|u)
static constexpr size_t WS_NEED  = GU_OFF   + 77594624;     // 353370112
// scratch overlays (all uses are on dead regions at that point in the stream):
//   scrA = GU_OFF   (qkv e1/e2 split partials; GU not yet written)
//   scrB = QKV_OFF  (wo / gu-e2 / wd split partials; qkv/Qb/Kb/Vt dead by then)

// ---------------- weight cast: 21 matrices, one launch ----------------
struct CastTab { const float* src[21]; int pre[22]; };

__global__ __launch_bounds__(256) void cast_weights(CastTab tab, u16* __restrict__ dst) {
  int c = blockIdx.x;            // chunk of 32768 elems
  int a = 0;
  while (c >= tab.pre[a + 1]) a++;
  const f32x4* s = (const f32x4*)(tab.src[a] + ((size_t)(c - tab.pre[a]) << 15));
  u16x4* d = (u16x4*)(dst + ((size_t)c << 15));
  int t = threadIdx.x;
  for (int i = t; i < 8192; i += 256) {
    f32x4 v = s[i];
    u16x4 o; o[0] = f2bf(v[0]); o[1] = f2bf(v[1]); o[2] = f2bf(v[2]); o[3] = f2bf(v[3]);
    d[i] = o;
  }
}

// ---------------- RMSNorm (f32 in) -> bf16 out ----------------
__global__ __launch_bounds__(256) void rmsnorm_cast(
    const float* __restrict__ x, const float* __restrict__ w,
    u16* __restrict__ out, int hid) {
  int row = blockIdx.x;
  const f32x4* xr = (const f32x4*)(x + (size_t)row * hid);
  const f32x4* wr = (const f32x4*)w;
  int n4 = hid >> 2;
  int t = threadIdx.x;
  float ss = 0.f;
  for (int i = t; i < n4; i += 256) {
    f32x4 v = xr[i];
    ss += v[0] * v[0] + v[1] * v[1] + v[2] * v[2] + v[3] * v[3];
  }
#pragma unroll
  for (int m = 1; m < 64; m <<= 1) ss += __shfl_xor(ss, m);
  __shared__ float part[4];
  if ((t & 63) == 0) part[t >> 6] = ss;
  __syncthreads();
  float tot = part[0] + part[1] + part[2] + part[3];
  float rs = rsqrtf(tot / (float)hid + 1e-6f);
  u16x4* orow = (u16x4*)(out + (size_t)row * hid);
  for (int i = t; i < n4; i += 256) {
    f32x4 v = xr[i];
    f32x4 g = wr[i];
    u16x4 o;
    o[0] = f2bf(v[0] * rs * g[0]); o[1] = f2bf(v[1] * rs * g[1]);
    o[2] = f2bf(v[2] * rs * g[2]); o[3] = f2bf(v[3] * rs * g[3]);
    orow[i] = o;
  }
}

// ---------------- GEMM: C(MxN) = A(MxK) * B(N,K)^T, bf16 in, m97 structure ----
// A row gather: grow = (r>>logSe)*bstride + (r & mask) + rowoff; A row stride
// = Astride elems (allows strided g-half of fused GU buffer).
// SPLIT: blockIdx.z picks K-chunk [z*kLen, z*kLen+kLen); partial f32 ->
//        ((float*)C) + z*mn. Non-split: kLen == K.
// RESID (non-split only): 0 none; 1 add R[]; 2 add C[] in place.
// OUTBF (non-split only): 1 -> bf16 C; 0 -> f32 C.
template <int RESID, int OUTBF, bool SPLIT>
__global__ __launch_bounds__(256) void gemm_bt(
    const u16* __restrict__ A, int Astride, int logSe, int bstride, int rowoff,
    const u16* __restrict__ Bw, int K, int kLen, int N,
    void* __restrict__ C, const float* __restrict__ R, size_t mn) {
  __shared__ u16 As[128 * 64];
  __shared__ u16 Bs[128 * 64];
  const int t = threadIdx.x;

  // bijective XCD swizzle (m204)
  int gx = gridDim.x, nwg = gx * gridDim.y;
  int flat = blockIdx.y * gx + blockIdx.x;
  int q = nwg >> 3, r8 = nwg & 7;
  int xcd = flat & 7, idx = flat >> 3;
  int nf = (xcd < r8 ? xcd * (q + 1) : r8 * (q + 1) + (xcd - r8) * q) + idx;
  const int nt = nf % gx, mt = nf / gx;

  const int w = t >> 6, l = t & 63;
  const int wr = (w >> 1) * 64, wc = (w & 1) * 64;
  const int l15 = l & 15, lg = l >> 4;
  f32x4 acc[4][4];
#pragma unroll
  for (int i = 0; i < 4; i++)
#pragma unroll
    for (int j = 0; j < 4; j++) acc[i][j] = (f32x4){0.f, 0.f, 0.f, 0.f};

  const int sr = t >> 3, su0 = t & 7;
  const int mask_se = (1 << logSe) - 1;
  const int k0 = SPLIT ? (int)blockIdx.z * kLen : 0;
  const int k1 = k0 + kLen;

  for (int kt = k0; kt < k1; kt += 64) {
    __syncthreads();
#pragma unroll
    for (int i = 0; i < 4; i++) {
      int row = i * 32 + sr;
      int gr = mt * 128 + row;
      int grow = ((gr >> logSe) * bstride) + (gr & mask_se) + rowoff;
      int su = su0 ^ (row & 7);
      gl_lds16(A + (size_t)grow * Astride + kt + su * 8, &As[row * 64 + su0 * 8]);
    }
#pragma unroll
    for (int i = 0; i < 4; i++) {
      int row = i * 32 + sr;
      int gc = nt * 128 + row;
      int su = su0 ^ (row & 7);
      gl_lds16(Bw + (size_t)gc * K + kt + su * 8, &Bs[row * 64 + su0 * 8]);
    }
    __syncthreads();

    s16x8 af[2][4], bfr[2][4];
#pragma unroll
    for (int mi = 0; mi < 4; mi++) {
      int row = wr + mi * 16 + l15;
#pragma unroll
      for (int ks = 0; ks < 2; ks++) {
        int u = ks * 4 + lg;
        af[ks][mi] = *(const s16x8*)&As[row * 64 + (u ^ (row & 7)) * 8];
      }
    }
#pragma unroll
    for (int ni = 0; ni < 4; ni++) {
      int row = wc + ni * 16 + l15;
#pragma unroll
      for (int ks = 0; ks < 2; ks++) {
        int u = ks * 4 + lg;
        bfr[ks][ni] = *(const s16x8*)&Bs[row * 64 + (u ^ (row & 7)) * 8];
      }
    }
#pragma unroll
    for (int ks = 0; ks < 2; ks++)
#pragma unroll
      for (int mi = 0; mi < 4; mi++)
#pragma unroll
        for (int ni = 0; ni < 4; ni++)
          acc[mi][ni] = mfma16(af[ks][mi], bfr[ks][ni], acc[mi][ni]);
  }

  float* Pz = SPLIT ? ((float*)C + (size_t)blockIdx.z * mn) : nullptr;
#pragma unroll
  for (int mi = 0; mi < 4; mi++) {
#pragma unroll
    for (int r = 0; r < 4; r++) {
      int crow = mt * 128 + wr + mi * 16 + lg * 4 + r;
      size_t rb = (size_t)crow * N;
#pragma unroll
      for (int ni = 0; ni < 4; ni++) {
        int col = nt * 128 + wc + ni * 16 + l15;
        float v = acc[mi][ni][r];
        if (SPLIT) {
          Pz[rb + col] = v;
        } else {
          if (RESID == 1) v += R[rb + col];
          if (RESID == 2) v += ((const float*)C)[rb + col];
          if (OUTBF) ((u16*)C)[rb + col] = f2bf(v);
          else       ((float*)C)[rb + col] = v;
        }
      }
    }
  }
}

// ---------------- split-K reduce (fixed order -> deterministic) ----------------
// RESID: 0 none; 1 add R; 2 add C in place. OUTBF: 1 bf16 out, 0 f32 out.
template <int RESID, int OUTBF>
__global__ __launch_bounds__(256) void reduce_split(
    const float* __restrict__ part, int nz, size_t mn4,
    void* __restrict__ C, const float* __restrict__ R) {
  const f32x4* p4 = (const f32x4*)part;
  for (size_t i = (size_t)blockIdx.x * 256 + threadIdx.x; i < mn4;
       i += (size_t)gridDim.x * 256) {
    f32x4 s = p4[i];
    for (int z = 1; z < nz; z++) s += p4[(size_t)z * mn4 + i];
    if (RESID == 1) s += ((const f32x4*)R)[i];
    if (RESID == 2) s += ((const f32x4*)C)[i];
    if (OUTBF) {
      u16x4 o; o[0] = f2bf(s[0]); o[1] = f2bf(s[1]); o[2] = f2bf(s[2]); o[3] = f2bf(s[3]);
      ((u16x4*)C)[i] = o;
    } else {
      ((f32x4*)C)[i] = s;
    }
  }
}

// ---------------- QK norm + RoPE + scatter (fused-QKV layout) ----------------
__global__ __launch_bounds__(256) void qk_rope(
    const u16* __restrict__ qkv,
    const float* __restrict__ qn0, const float* __restrict__ qn1, const float* __restrict__ qn2,
    const float* __restrict__ kn0, const float* __restrict__ kn1, const float* __restrict__ kn2,
    const int* __restrict__ pos, u16* __restrict__ Q, u16* __restrict__ K) {
  int tk = blockIdx.x;
  int b = tk / 1344, sg = tk % 1344;
  int w = threadIdx.x >> 6, l = threadIdx.x & 63;
  int hr = blockIdx.y * 4 + w;           // 0..15 q heads, 16..23 k heads
  int e, off, Se;
  if (sg < 1024)      { e = 0; off = 0;    Se = 1024; }
  else if (sg < 1280) { e = 1; off = 1024; Se = 256;  }
  else                { e = 2; off = 1280; Se = 64;   }
  int r = b * Se + (sg - off);
  size_t rowbase = (e == 0) ? 0 : (e == 1) ? 8388608 : 10485760;  // elems
  const u16* src; const float* nw; u16* dst;
  if (hr < 16) {
    src = qkv + rowbase + (size_t)r * 4096 + hr * 128;
    nw = (e == 0) ? qn0 : (e == 1) ? qn1 : qn2;
    dst = Q + ((size_t)(b * 16 + hr) * 1344 + sg) * 128;
  } else {
    int kh = hr - 16;
    src = qkv + rowbase + (size_t)r * 4096 + 2048 + kh * 128;
    nw = (e == 0) ? kn0 : (e == 1) ? kn1 : kn2;
    dst = K + ((size_t)(b * 8 + kh) * 1344 + sg) * 128;
  }
  float x0v = bf2f(src[l]), x1v = bf2f(src[l + 64]);
  float ss = x0v * x0v + x1v * x1v;
#pragma unroll
  for (int m = 1; m < 64; m <<= 1) ss += __shfl_xor(ss, m);
  float rs = rsqrtf(ss * (1.f / 128.f) + 1e-6f);
  float y0 = x0v * rs * nw[l], y1 = x1v * rs * nw[l + 64];
  float p = (float)pos[b * 1344 + sg];
  float inv = exp2f(-(float)l * 0.3114307588956902f);  // log2(1e6)/64
  float th = p * inv;
  float c = cosf(th), s = sinf(th);
  dst[l]      = f2bf(y0 * c - y1 * s);
  dst[l + 64] = f2bf(y1 * c + y0 * s);
}

// ---------------- V transpose: fused-QKV -> (B,KV,D,S) ----------------
__global__ __launch_bounds__(256) void v_trans(const u16* __restrict__ qkv, u16* __restrict__ Vt) {
  __shared__ u16 tile[64][72];
  int st = blockIdx.x;
  int b = st / 21, s0 = (st % 21) * 64;
  int kvh = blockIdx.y >> 1, dh = (blockIdx.y & 1) * 64;
  int t = threadIdx.x;
  int sl = t >> 2, d0 = (t & 3) * 16;
  int sg = s0 + sl;
  int e, off, Se;
  if (sg < 1024)      { e = 0; off = 0;    Se = 1024; }
  else if (sg < 1280) { e = 1; off = 1024; Se = 256;  }
  else                { e = 2; off = 1280; Se = 64;   }
  int r = b * Se + (sg - off);
  size_t rowbase = (e == 0) ? 0 : (e == 1) ? 8388608 : 10485760;  // elems
  const u16* src = qkv + rowbase + (size_t)r * 4096 + 3072 + kvh * 128 + dh + d0;
  u16x8 a = *(const u16x8*)src;
  u16x8 bb = *(const u16x8*)(src + 8);
#pragma unroll
  for (int j = 0; j < 8; j++) { tile[sl][d0 + j] = a[j]; tile[sl][d0 + 8 + j] = bb[j]; }
  __syncthreads();
  int dl = t >> 2, sb = (t & 3) * 16;
  u16* dst = Vt + ((size_t)(b * 8 + kvh) * 128 + dh + dl) * 1344 + s0 + sb;
  u16x8 o0, o1;
#pragma unroll
  for (int j = 0; j < 8; j++) { o0[j] = tile[sb + j][dl]; o1[j] = tile[sb + 8 + j][dl]; }
  *(u16x8*)dst = o0;
  *(u16x8*)(dst + 8) = o1;
}

// ---------------- Flash attention: Q(B,H,S,D), K(B,KV,S,D), Vt(B,KV,D,S) ------
__global__ __launch_bounds__(256, 2) void attn(
    const u16* __restrict__ Q, const u16* __restrict__ K, const u16* __restrict__ Vt,
    const float* __restrict__ mask, u16* __restrict__ attO) {
  constexpr int S = 1344;
  __shared__ u16 Qs[64 * 128];
  __shared__ u16 Ks[64 * 128];
  __shared__ u16 Vts[128 * 64];
  __shared__ u16 Ps[4][16 * 64];
  int bh = blockIdx.y;
  int b = bh >> 4, h = bh & 15, kvh = h >> 1;
  int q0 = blockIdx.x * 64;
  int t = threadIdx.x, w = t >> 6, l = t & 63;
  const int l15 = l & 15, lg = l >> 4;
  const u16* Qg = Q + ((size_t)(b * 16 + h) * S + q0) * 128;
  const u16* Kg = K + ((size_t)(b * 8 + kvh) * S) * 128;
  const u16* Vg = Vt + ((size_t)(b * 8 + kvh) * 128) * S;

  {
    int unit = t & 15, r16 = t >> 4;
#pragma unroll
    for (int i = 0; i < 4; i++) {
      int row = i * 16 + r16;
      int su = (unit & 8) | ((unit & 7) ^ (row & 7));
      gl_lds16(Qg + (size_t)row * 128 + su * 8, &Qs[row * 128 + unit * 8]);
    }
  }
  __syncthreads();
  s16x8 qf[4];
  {
    int qrow = w * 16 + l15;
#pragma unroll
    for (int ks = 0; ks < 4; ks++) {
      int u = ks * 4 + lg;
      int su = (u & 8) | ((u & 7) ^ (qrow & 7));
      qf[ks] = *(const s16x8*)&Qs[qrow * 128 + su * 8];
    }
  }

  float mrow[4] = {-3e38f, -3e38f, -3e38f, -3e38f};
  float lrow[4] = {0.f, 0.f, 0.f, 0.f};
  f32x4 of[8];
#pragma unroll
  for (int d = 0; d < 8; d++) of[d] = (f32x4){0.f, 0.f, 0.f, 0.f};
  const float scale = 0.08838834764831845f;

  for (int kt = 0; kt < 21; ++kt) {
    int k0 = kt * 64;
    __syncthreads();
    {
      int unit = t & 15, r16 = t >> 4;
#pragma unroll
      for (int i = 0; i < 4; i++) {
        int row = i * 16 + r16;
        int su = (unit & 8) | ((unit & 7) ^ (row & 7));
        gl_lds16(Kg + (size_t)(k0 + row) * 128 + su * 8, &Ks[row * 128 + unit * 8]);
      }
      int u8 = t & 7, r32 = t >> 3;
#pragma unroll
      for (int i = 0; i < 4; i++) {
        int row = i * 32 + r32;
        int su = u8 ^ (row & 7);
        gl_lds16(Vg + (size_t)row * S + k0 + su * 8, &Vts[row * 64 + u8 * 8]);
      }
    }
    __syncthreads();

    f32x4 sf[4];
#pragma unroll
    for (int cb = 0; cb < 4; cb++) {
      f32x4 a = (f32x4){0.f, 0.f, 0.f, 0.f};
      int krow = cb * 16 + l15;
#pragma unroll
      for (int ks = 0; ks < 4; ks++) {
        int u = ks * 4 + lg;
        int su = (u & 8) | ((u & 7) ^ (krow & 7));
        s16x8 kf = *(const s16x8*)&Ks[krow * 128 + su * 8];
        a = mfma16(qf[ks], kf, a);
      }
      sf[cb] = a;
    }

    float pv[4][4], tmax[4];
    int qg0 = q0 + w * 16 + lg * 4;
#pragma unroll
    for (int r = 0; r < 4; r++) {
      const float* mp = mask + ((size_t)(b * S + qg0 + r)) * S + k0 + l15;
      float v0 = sf[0][r] * scale + mp[0];
      float v1 = sf[1][r] * scale + mp[16];
      float v2 = sf[2][r] * scale + mp[32];
      float v3 = sf[3][r] * scale + mp[48];
      pv[0][r] = v0; pv[1][r] = v1; pv[2][r] = v2; pv[3][r] = v3;
      tmax[r] = fmaxf(fmaxf(v0, v1), fmaxf(v2, v3));
    }
#pragma unroll
    for (int m = 1; m < 16; m <<= 1)
#pragma unroll
      for (int r = 0; r < 4; r++) tmax[r] = fmaxf(tmax[r], __shfl_xor(tmax[r], m));

    float fr[4];
#pragma unroll
    for (int r = 0; r < 4; r++) {
      float mnew = fmaxf(mrow[r], tmax[r]);
      fr[r] = __expf(mrow[r] - mnew);
      mrow[r] = mnew;
      float rs = 0.f;
#pragma unroll
      for (int cb = 0; cb < 4; cb++) { pv[cb][r] = __expf(pv[cb][r] - mnew); rs += pv[cb][r]; }
#pragma unroll
      for (int m = 1; m < 16; m <<= 1) rs += __shfl_xor(rs, m);
      lrow[r] = lrow[r] * fr[r] + rs;
    }
#pragma unroll
    for (int d = 0; d < 8; d++)
#pragma unroll
      for (int r = 0; r < 4; r++) of[d][r] *= fr[r];

#pragma unroll
    for (int cb = 0; cb < 4; cb++)
#pragma unroll
      for (int r = 0; r < 4; r++) {
        int prow = lg * 4 + r;
        int col = cb * 16 + l15;
        int su = (col >> 3) ^ (prow & 7);
        Ps[w][prow * 64 + su * 8 + (col & 7)] = f2bf(pv[cb][r]);
      }
    __syncthreads();

    s16x8 pa[2];
#pragma unroll
    for (int ks = 0; ks < 2; ks++) {
      int prow = l15;
      int u = ks * 4 + lg;
      pa[ks] = *(const s16x8*)&Ps[w][prow * 64 + (u ^ (prow & 7)) * 8];
    }
#pragma unroll
    for (int d = 0; d < 8; d++) {
      int vrow = d * 16 + l15;
#pragma unroll
      for (int ks = 0; ks < 2; ks++) {
        int u = ks * 4 + lg;
        s16x8 vf = *(const s16x8*)&Vts[vrow * 64 + (u ^ (vrow & 7)) * 8];
        of[d] = mfma16(pa[ks], vf, of[d]);
      }
    }
  }

#pragma unroll
  for (int r = 0; r < 4; r++) {
    float il = 1.f / lrow[r];
    int sg = q0 + w * 16 + lg * 4 + r;
    u16* orow = attO + ((size_t)(b * S + sg)) * 2048 + h * 128;
#pragma unroll
    for (int d = 0; d < 8; d++) orow[d * 16 + l15] = f2bf(of[d][r] * il);
  }
}

// ---------------- silu(g)*u on fused GU buffer (m written over g half) -------
__global__ __launch_bounds__(256) void silu_fused(u16* __restrict__ gu, int F8, long total8) {
  long i = (long)blockIdx.x * 256 + threadIdx.x;
  if (i >= total8) return;
  long row = i / F8;
  int c8 = (int)(i - row * F8);
  size_t base = (size_t)row * (F8 * 16) + (size_t)c8 * 8;  // row stride 2F elems
  u16x8 gv = *(const u16x8*)(gu + base);
  u16x8 uv = *(const u16x8*)(gu + base + (size_t)F8 * 8);
  u16x8 o;
#pragma unroll
  for (int j = 0; j < 8; j++) {
    float gf = bf2f(gv[j]), uf = bf2f(uv[j]);
    float s = gf / (1.f + __expf(-gf));
    o[j] = f2bf(s * uf);
  }
  *(u16x8*)(gu + base) = o;
}

// ---------------------------------------------------------------------------
extern "C" void kernel_launch(void* const* d_in, const int* in_sizes, int n_in,
                              void* d_out, int out_size, void* d_ws, size_t ws_size,
                              hipStream_t stream) {
  if (ws_size < WS_NEED) return;

  const float* x[3] = {(const float*)d_in[0], (const float*)d_in[1], (const float*)d_in[2]};
  const float* mask = (const float*)d_in[3];
  const int* pos = (const int*)d_in[4];
  auto W = [&](int e, int k) -> const float* { return (const float*)d_in[5 + e * 11 + k]; };
  // k: 0 ln1, 1 ln2, 2 wq, 3 wk, 4 wv, 5 wo, 6 qn, 7 kn, 8 wg, 9 wu, 10 wd

  char* ws = (char*)d_ws;
  u16* wbf  = (u16*)(ws + WB_OFF);
  u16* h1   = (u16*)(ws + H1_OFF);
  u16* h2   = (u16*)(ws + H2_OFF);
  u16* qkv  = (u16*)(ws + QKV_OFF);
  u16* Qb   = (u16*)(ws + QB_OFF);
  u16* Kb   = (u16*)(ws + KB_OFF);
  u16* Vtb  = (u16*)(ws + VT_OFF);
  u16* attO = (u16*)(ws + ATTO_OFF);
  u16* gu   = (u16*)(ws + GU_OFF);
  float* scrA = (float*)(ws + GU_OFF);    // 77.6MB dead until g/u GEMMs
  float* scrB = (float*)(ws + QKV_OFF);   // 44MB (qkv..Vt) dead after attn;
                                          // qkv region alone (22MB) dead after rope/v_trans
  float* dout = (float*)d_out;

  const int hid[3] = {2048, 1024, 1024}, ffn[3] = {8192, 4096, 4096};
  const int M[3] = {2048, 512, 128};
  const int logM[3] = {11, 9, 7}, logSe[3] = {10, 8, 6}, eoff[3] = {0, 1024, 1280};
  const size_t douto[3] = {0, 4194304, 4718592};       // f32 elems, also h1/h2 elem offs
  const size_t qkvo[3]  = {0, 8388608, 10485760};      // elems (rows*4096)
  const size_t guo[3]   = {0, 33554432, 37748736};     // elems (rows*2F)

  // weight table + bf16 offsets (order per expert: wq,wk,wv,wo,wg,wu,wd)
  size_t woff[3][7];
  CastTab tab;
  {
    size_t cum = 0; int cc = 0, ci = 0;
    for (int e = 0; e < 3; e++) {
      const int kidx[7] = {2, 3, 4, 5, 8, 9, 10};
      const size_t sz[7] = {(size_t)2048 * hid[e], (size_t)1024 * hid[e], (size_t)1024 * hid[e],
                            (size_t)2048 * hid[e], (size_t)ffn[e] * hid[e],
                            (size_t)ffn[e] * hid[e], (size_t)ffn[e] * hid[e]};
      for (int j = 0; j < 7; j++) {
        woff[e][j] = cum;
        tab.src[ci] = W(e, kidx[j]);
        tab.pre[ci] = cc;
        cum += sz[j];
        cc += (int)(sz[j] >> 15);
        ci++;
      }
    }
    tab.pre[21] = cc;  // 3072 chunks
  }

  auto rgrid = [](size_t mn4) -> unsigned {
    size_t g = (mn4 + 255) >> 8;
    return (unsigned)(g > 2048 ? 2048 : g);
  };

  // 1. weights -> bf16
  cast_weights<<<dim3(3072), dim3(256), 0, stream>>>(tab, wbf);

  // 2. RMSNorm(ln1) -> h1
  for (int e = 0; e < 3; e++)
    rmsnorm_cast<<<dim3(M[e]), dim3(256), 0, stream>>>(x[e], W(e, 0), h1 + douto[e], hid[e]);

  // 3. fused QKV projections (N=4096: q|k|v rows contiguous in wbf)
  gemm_bt<0, 1, false><<<dim3(32, 16), dim3(256), 0, stream>>>(
      h1, 2048, 11, 0, 0, wbf + woff[0][0], 2048, 2048, 4096, qkv, nullptr, 0);
  gemm_bt<0, 0, true><<<dim3(32, 4, 2), dim3(256), 0, stream>>>(
      h1 + douto[1], 1024, 9, 0, 0, wbf + woff[1][0], 1024, 512, 4096, scrA, nullptr,
      (size_t)512 * 4096);
  reduce_split<0, 1><<<rgrid(524288), dim3(256), 0, stream>>>(
      scrA, 2, 524288, qkv + qkvo[1], nullptr);
  gemm_bt<0, 0, true><<<dim3(32, 1, 8), dim3(256), 0, stream>>>(
      h1 + douto[2], 1024, 7, 0, 0, wbf + woff[2][0], 1024, 128, 4096, scrA, nullptr,
      (size_t)128 * 4096);
  reduce_split<0, 1><<<rgrid(131072), dim3(256), 0, stream>>>(
      scrA, 8, 131072, qkv + qkvo[2], nullptr);

  // 4. q/k norm + rope + scatter; V transpose
  qk_rope<<<dim3(2688, 6), dim3(256), 0, stream>>>(
      qkv, W(0, 6), W(1, 6), W(2, 6), W(0, 7), W(1, 7), W(2, 7), pos, Qb, Kb);
  v_trans<<<dim3(42, 16), dim3(256), 0, stream>>>(qkv, Vtb);

  // 5. attention
  attn<<<dim3(21, 32), dim3(256), 0, stream>>>(Qb, Kb, Vtb, mask, attO);

  // 6. o = att @ wo^T + x -> d_out (f32), split-K
  gemm_bt<0, 0, true><<<dim3(16, 16, 2), dim3(256), 0, stream>>>(
      attO, 2048, 10, 1344, 0, wbf + woff[0][3], 2048, 1024, 2048, scrB, nullptr,
      (size_t)4194304);
  reduce_split<1, 0><<<rgrid(1048576), dim3(256), 0, stream>>>(
      scrB, 2, 1048576, dout, x[0]);
  gemm_bt<0, 0, true><<<dim3(8, 4, 8), dim3(256), 0, stream>>>(
      attO, 2048, 8, 1344, 1024, wbf + woff[1][3], 2048, 256, 1024, scrB, nullptr,
      (size_t)524288);
  reduce_split<1, 0><<<rgrid(131072), dim3(256), 0, stream>>>(
      scrB, 8, 131072, dout + douto[1], x[1]);
  gemm_bt<0, 0, true><<<dim3(8, 1, 16), dim3(256), 0, stream>>>(
      attO, 2048, 6, 1344, 1280, wbf + woff[2][3], 2048, 128, 1024, scrB, nullptr,
      (size_t)131072);
  reduce_split<1, 0><<<rgrid(32768), dim3(256), 0, stream>>>(
      scrB, 16, 32768, dout + douto[2], x[2]);

  // 7. RMSNorm(ln2) -> h2
  for (int e = 0; e < 3; e++)
    rmsnorm_cast<<<dim3(M[e]), dim3(256), 0, stream>>>(dout + douto[e], W(e, 1),
                                                       h2 + douto[e], hid[e]);

  // 8. fused g|u projections (N=2*ffn: wg|wu rows contiguous in wbf)
  gemm_bt<0, 1, false><<<dim3(128, 16), dim3(256), 0, stream>>>(
      h2, 2048, 11, 0, 0, wbf + woff[0][4], 2048, 2048, 16384, gu, nullptr, 0);
  gemm_bt<0, 1, false><<<dim3(64, 4), dim3(256), 0, stream>>>(
      h2 + douto[1], 1024, 9, 0, 0, wbf + woff[1][4], 1024, 1024, 8192, gu + guo[1],
      nullptr, 0);
  gemm_bt<0, 0, true><<<dim3(64, 1, 4), dim3(256), 0, stream>>>(
      h2 + douto[2], 1024, 7, 0, 0, wbf + woff[2][4], 1024, 256, 8192, scrB, nullptr,
      (size_t)1048576);
  reduce_split<0, 1><<<rgrid(262144), dim3(256), 0, stream>>>(
      scrB, 4, 262144, gu + guo[2], nullptr);

  // 9. m = silu(g)*u (in place over g half)
  silu_fused<<<dim3(8192), dim3(256), 0, stream>>>(gu, 1024, 2097152L);
  silu_fused<<<dim3(1024), dim3(256), 0, stream>>>(gu + guo[1], 512, 262144L);
  silu_fused<<<dim3(256), dim3(256), 0, stream>>>(gu + guo[2], 512, 65536L);

  // 10. out += m @ wd^T (A = g-half of GU, row stride 2F), split-K
  gemm_bt<0, 0, true><<<dim3(16, 16, 2), dim3(256), 0, stream>>>(
      gu, 16384, 11, 0, 0, wbf + woff[0][6], 8192, 4096, 2048, scrB, nullptr,
      (size_t)4194304);
  reduce_split<2, 0><<<rgrid(1048576), dim3(256), 0, stream>>>(
      scrB, 2, 1048576, dout, nullptr);
  gemm_bt<0, 0, true><<<dim3(8, 4, 8), dim3(256), 0, stream>>>(
      gu + guo[1], 8192, 9, 0, 0, wbf + woff[1][6], 4096, 512, 1024, scrB, nullptr,
      (size_t)524288);
  reduce_split<2, 0><<<rgrid(131072), dim3(256), 0, stream>>>(
      scrB, 8, 131072, dout + douto[1], nullptr);
  gemm_bt<0, 0, true><<<dim3(8, 1, 16), dim3(256), 0, stream>>>(
      gu + guo[2], 8192, 7, 0, 0, wbf + woff[2][6], 4096, 256, 1024, scrB, nullptr,
      (size_t)131072);
  reduce_split<2, 0><<<rgrid(32768), dim3(256), 0, stream>>>(
      scrB, 16, 32768, dout + douto[2], nullptr);
}

// Round 3
// 809.401 us; speedup vs baseline: 1.6630x; 1.0061x over previous
//
#include <hip/hip_runtime.h>
#include <cstdint>
#include <cstddef>

// ---------------------------------------------------------------------------
// Qwen3VL-with-experts fused forward, bf16 MFMA. Round 3:
// 256x256 8-phase counted-vmcnt GEMM (T2+T3+T4+T5) for the four e0 GEMMs;
// 128x128 m97-structure GEMM kept for e1/e2; split-K two-pass reduce.
// ---------------------------------------------------------------------------

using u16 = unsigned short;
typedef __attribute__((ext_vector_type(4))) float  f32x4;
typedef __attribute__((ext_vector_type(4))) u16    u16x4;
typedef __attribute__((ext_vector_type(8))) u16    u16x8;
typedef __attribute__((ext_vector_type(8))) short  s16x8;

__device__ __forceinline__ u16 f2bf(float f) {
  unsigned u = __builtin_bit_cast(unsigned, f);
  u = (u + 0x7FFF + ((u >> 16) & 1)) >> 16;
  return (u16)u;
}
__device__ __forceinline__ float bf2f(u16 h) {
  unsigned u = ((unsigned)h) << 16;
  return __builtin_bit_cast(float, u);
}
__device__ __forceinline__ f32x4 mfma16(s16x8 a, s16x8 b, f32x4 c) {
  return __builtin_amdgcn_mfma_f32_16x16x32_bf16(a, b, c, 0, 0, 0);
}
__device__ __forceinline__ void gl_lds16(const u16* g, u16* l) {
  __builtin_amdgcn_global_load_lds(
      (const __attribute__((address_space(1))) unsigned int*)g,
      (__attribute__((address_space(3))) unsigned int*)l, 16, 0, 0);
}

// ---------------- workspace layout (bytes) ----------------
static constexpr size_t WB_OFF   = 0;                       // bf16 weights 201326592
static constexpr size_t H1_OFF   = WB_OFF   + 201326592;    // 9699328
static constexpr size_t H2_OFF   = H1_OFF   + 9699328;      // 9699328
static constexpr size_t QKV_OFF  = H2_OFF   + 9699328;      // 22020096
static constexpr size_t QB_OFF   = QKV_OFF  + 22020096;     // 11010048
static constexpr size_t KB_OFF   = QB_OFF   + 11010048;     // 5505024
static constexpr size_t VT_OFF   = KB_OFF   + 5505024;      // 5505024
static constexpr size_t ATTO_OFF = VT_OFF   + 5505024;      // 11010048
static constexpr size_t GU_OFF   = ATTO_OFF + 11010048;     // 77594624
static constexpr size_t WS_NEED  = GU_OFF   + 77594624;     // 353370112
// scratch overlays (dead at point of use):
//   scrA = GU_OFF  (QKV partials, WO-e0 partials; GU written later)
//   scrB = QKV_OFF (44MB span QKV..VT, dead after attn: e1/e2 partials)
//   scrC = H1_OFF  (74MB span H1..ATTO, dead at WD time: WD-e0 partials)

// ---------------- weight cast ----------------
struct CastTab { const float* src[21]; int pre[22]; };

__global__ __launch_bounds__(256) void cast_weights(CastTab tab, u16* __restrict__ dst) {
  int c = blockIdx.x;
  int a = 0;
  while (c >= tab.pre[a + 1]) a++;
  const f32x4* s = (const f32x4*)(tab.src[a] + ((size_t)(c - tab.pre[a]) << 15));
  u16x4* d = (u16x4*)(dst + ((size_t)c << 15));
  int t = threadIdx.x;
  for (int i = t; i < 8192; i += 256) {
    f32x4 v = s[i];
    u16x4 o; o[0] = f2bf(v[0]); o[1] = f2bf(v[1]); o[2] = f2bf(v[2]); o[3] = f2bf(v[3]);
    d[i] = o;
  }
}

// ---------------- RMSNorm (f32 in) -> bf16 out ----------------
__global__ __launch_bounds__(256) void rmsnorm_cast(
    const float* __restrict__ x, const float* __restrict__ w,
    u16* __restrict__ out, int hid) {
  int row = blockIdx.x;
  const f32x4* xr = (const f32x4*)(x + (size_t)row * hid);
  const f32x4* wr = (const f32x4*)w;
  int n4 = hid >> 2;
  int t = threadIdx.x;
  float ss = 0.f;
  for (int i = t; i < n4; i += 256) {
    f32x4 v = xr[i];
    ss += v[0] * v[0] + v[1] * v[1] + v[2] * v[2] + v[3] * v[3];
  }
#pragma unroll
  for (int m = 1; m < 64; m <<= 1) ss += __shfl_xor(ss, m);
  __shared__ float part[4];
  if ((t & 63) == 0) part[t >> 6] = ss;
  __syncthreads();
  float tot = part[0] + part[1] + part[2] + part[3];
  float rs = rsqrtf(tot / (float)hid + 1e-6f);
  u16x4* orow = (u16x4*)(out + (size_t)row * hid);
  for (int i = t; i < n4; i += 256) {
    f32x4 v = xr[i];
    f32x4 g = wr[i];
    u16x4 o;
    o[0] = f2bf(v[0] * rs * g[0]); o[1] = f2bf(v[1] * rs * g[1]);
    o[2] = f2bf(v[2] * rs * g[2]); o[3] = f2bf(v[3] * rs * g[3]);
    orow[i] = o;
  }
}

// ---------------- 128x128 GEMM (m97 structure) for e1/e2 ----------------
template <int RESID, int OUTBF, bool SPLIT>
__global__ __launch_bounds__(256) void gemm_bt(
    const u16* __restrict__ A, int Astride, int logSe, int bstride, int rowoff,
    const u16* __restrict__ Bw, int K, int kLen, int N,
    void* __restrict__ C, const float* __restrict__ R, size_t mn) {
  __shared__ u16 As[128 * 64];
  __shared__ u16 Bs[128 * 64];
  const int t = threadIdx.x;

  int gx = gridDim.x, nwg = gx * gridDim.y;
  int flat = blockIdx.y * gx + blockIdx.x;
  int q = nwg >> 3, r8 = nwg & 7;
  int xcd = flat & 7, idx = flat >> 3;
  int nf = (xcd < r8 ? xcd * (q + 1) : r8 * (q + 1) + (xcd - r8) * q) + idx;
  const int nt = nf % gx, mt = nf / gx;

  const int w = t >> 6, l = t & 63;
  const int wr = (w >> 1) * 64, wc = (w & 1) * 64;
  const int l15 = l & 15, lg = l >> 4;
  f32x4 acc[4][4];
#pragma unroll
  for (int i = 0; i < 4; i++)
#pragma unroll
    for (int j = 0; j < 4; j++) acc[i][j] = (f32x4){0.f, 0.f, 0.f, 0.f};

  const int sr = t >> 3, su0 = t & 7;
  const int mask_se = (1 << logSe) - 1;
  const int k0 = SPLIT ? (int)blockIdx.z * kLen : 0;
  const int k1 = k0 + kLen;

  for (int kt = k0; kt < k1; kt += 64) {
    __syncthreads();
#pragma unroll
    for (int i = 0; i < 4; i++) {
      int row = i * 32 + sr;
      int gr = mt * 128 + row;
      int grow = ((gr >> logSe) * bstride) + (gr & mask_se) + rowoff;
      int su = su0 ^ (row & 7);
      gl_lds16(A + (size_t)grow * Astride + kt + su * 8, &As[row * 64 + su0 * 8]);
    }
#pragma unroll
    for (int i = 0; i < 4; i++) {
      int row = i * 32 + sr;
      int gc = nt * 128 + row;
      int su = su0 ^ (row & 7);
      gl_lds16(Bw + (size_t)gc * K + kt + su * 8, &Bs[row * 64 + su0 * 8]);
    }
    __syncthreads();

    s16x8 af[2][4], bfr[2][4];
#pragma unroll
    for (int mi = 0; mi < 4; mi++) {
      int row = wr + mi * 16 + l15;
#pragma unroll
      for (int ks = 0; ks < 2; ks++) {
        int u = ks * 4 + lg;
        af[ks][mi] = *(const s16x8*)&As[row * 64 + (u ^ (row & 7)) * 8];
      }
    }
#pragma unroll
    for (int ni = 0; ni < 4; ni++) {
      int row = wc + ni * 16 + l15;
#pragma unroll
      for (int ks = 0; ks < 2; ks++) {
        int u = ks * 4 + lg;
        bfr[ks][ni] = *(const s16x8*)&Bs[row * 64 + (u ^ (row & 7)) * 8];
      }
    }
#pragma unroll
    for (int ks = 0; ks < 2; ks++)
#pragma unroll
      for (int mi = 0; mi < 4; mi++)
#pragma unroll
        for (int ni = 0; ni < 4; ni++)
          acc[mi][ni] = mfma16(af[ks][mi], bfr[ks][ni], acc[mi][ni]);
  }

  float* Pz = SPLIT ? ((float*)C + (size_t)blockIdx.z * mn) : nullptr;
#pragma unroll
  for (int mi = 0; mi < 4; mi++) {
#pragma unroll
    for (int r = 0; r < 4; r++) {
      int crow = mt * 128 + wr + mi * 16 + lg * 4 + r;
      size_t rb = (size_t)crow * N;
#pragma unroll
      for (int ni = 0; ni < 4; ni++) {
        int col = nt * 128 + wc + ni * 16 + l15;
        float v = acc[mi][ni][r];
        if (SPLIT) {
          Pz[rb + col] = v;
        } else {
          if (RESID == 1) v += R[rb + col];
          if (RESID == 2) v += ((const float*)C)[rb + col];
          if (OUTBF) ((u16*)C)[rb + col] = f2bf(v);
          else       ((float*)C)[rb + col] = v;
        }
      }
    }
  }
}

// ---------------- 256x256 8-phase GEMM (T2+T3+T4+T5) for e0 ----------------
// 8 waves (2Mx4N), per-wave 128x64 out. BK=64, double-buffered LDS 128 KiB.
// Counted vmcnt: stage tile T+2 into current buffer's dead regions:
//   ph1: A.q02 + B.lo (4 issues)  [dead after ph0]
//   ph2: B.hi (2)                  [dead after ph1]
//   ph3: A.q13 (2)                 [dead after ph2]
// Gates: end-ph0 vmcnt(10) [B.hi], end-ph1 vmcnt(12) [A.q13],
//        end-ph3 vmcnt(12) [next tile A.q02+B.lo]. Never 0 in-loop.
template <int MB, int N0>
__device__ __forceinline__ void mmblk(f32x4 (&acc)[8][4], const s16x8 (&afr)[2][4],
                                      const s16x8 (&bfr)[2][4]) {
#pragma unroll
  for (int ks = 0; ks < 2; ks++)
#pragma unroll
    for (int j = 0; j < 4; j++)
#pragma unroll
      for (int ni = 0; ni < 2; ni++)
        acc[MB + j][N0 + ni] =
            mfma16(afr[ks][j], bfr[ks][N0 + ni], acc[MB + j][N0 + ni]);
}

template <int RESID, int OUTBF, bool SPLIT>
__global__ __launch_bounds__(512, 2) void gemm256(
    const u16* __restrict__ A, int Astride, int logSe, int bstride, int rowoff,
    const u16* __restrict__ Bw, int K, int kLen, int N,
    void* __restrict__ C, const float* __restrict__ R, size_t mn) {
  __shared__ u16 As[2][256 * 64];
  __shared__ u16 Bs[2][256 * 64];
  const int t = threadIdx.x;

  int gx = gridDim.x, nwg = gx * gridDim.y;
  int flat = blockIdx.y * gx + blockIdx.x;
  int q = nwg >> 3, r8 = nwg & 7;
  int xcd = flat & 7, idx = flat >> 3;
  int nf = (xcd < r8 ? xcd * (q + 1) : r8 * (q + 1) + (xcd - r8) * q) + idx;
  const int nt = (nf % gx) * 256, mt = (nf / gx) * 256;

  const int w = t >> 6, l = t & 63;
  const int wm = (w >> 2) * 128, wn = (w & 3) * 64;
  const int l15 = l & 15, lg = l >> 4;
  const int sr8 = t >> 3, u8 = t & 7;
  const int mask_se = (1 << logSe) - 1;
  const int k0 = SPLIT ? (int)blockIdx.z * kLen : 0;
  const int kLast = k0 + kLen - 64;

  f32x4 acc[8][4];
#pragma unroll
  for (int i = 0; i < 8; i++)
#pragma unroll
    for (int j = 0; j < 4; j++) acc[i][j] = (f32x4){0.f, 0.f, 0.f, 0.f};

  auto stA = [&](int c, int qb, int ktv) {
    int row = qb + sr8;
    int gr = mt + row;
    int grow = ((gr >> logSe) * bstride) + (gr & mask_se) + rowoff;
    int su = u8 ^ (row & 7);
    gl_lds16(A + (size_t)grow * Astride + ktv + su * 8, &As[c][row * 64 + u8 * 8]);
  };
  auto stB = [&](int c, int half, int pair, int ktv) {
    int row = (pair * 2 + (t >> 8)) * 64 + half * 32 + ((t & 255) >> 3);
    int su = u8 ^ (row & 7);
    gl_lds16(Bw + (size_t)(nt + row) * K + ktv + su * 8, &Bs[c][row * 64 + u8 * 8]);
  };
  auto rdA = [&](int c, int mi, int ks) -> s16x8 {
    int row = wm + mi * 16 + l15;
    int u = ks * 4 + lg;
    return *(const s16x8*)&As[c][row * 64 + (u ^ (row & 7)) * 8];
  };
  auto rdB = [&](int c, int ni, int ks) -> s16x8 {
    int row = wn + ni * 16 + l15;
    int u = ks * 4 + lg;
    return *(const s16x8*)&Bs[c][row * 64 + (u ^ (row & 7)) * 8];
  };

  // prologue: stage tiles 0 (buf0) and 1 (buf1), steady-state order
  {
    int kt1 = k0 + 64;
    stA(0, 0, k0); stA(0, 128, k0);
    stB(0, 0, 0, k0); stB(0, 0, 1, k0);
    stB(0, 1, 0, k0); stB(0, 1, 1, k0);
    stA(0, 64, k0); stA(0, 192, k0);
    stA(1, 0, kt1); stA(1, 128, kt1);
    stB(1, 0, 0, kt1); stB(1, 0, 1, kt1);
    stB(1, 1, 0, kt1); stB(1, 1, 1, kt1);
    stA(1, 64, kt1); stA(1, 192, kt1);
  }
  asm volatile("s_waitcnt vmcnt(12)" ::: "memory");
  __builtin_amdgcn_s_barrier();
  __builtin_amdgcn_sched_barrier(0);

  s16x8 afr[2][4], bfr[2][4];
  int c = 0;
  for (int kt0 = k0; kt0 < k0 + kLen; kt0 += 64) {
    int ktp = kt0 + 128 <= kLast ? kt0 + 128 : kLast;  // tile T+2, clamped
    // ---- phase 0: read A m0-3, B n0-1; MFMA q(0,0)
#pragma unroll
    for (int ks = 0; ks < 2; ks++) {
#pragma unroll
      for (int j = 0; j < 4; j++) afr[ks][j] = rdA(c, j, ks);
#pragma unroll
      for (int j = 0; j < 2; j++) bfr[ks][j] = rdB(c, j, ks);
    }
    __builtin_amdgcn_s_setprio(1);
    mmblk<0, 0>(acc, afr, bfr);
    __builtin_amdgcn_s_setprio(0);
    asm volatile("s_waitcnt vmcnt(10)" ::: "memory");
    __builtin_amdgcn_s_barrier();
    __builtin_amdgcn_sched_barrier(0);
    // ---- phase 1: read B n2-3; stage A(T+2).q02 + B(T+2).lo; MFMA q(0,1)
#pragma unroll
    for (int ks = 0; ks < 2; ks++)
#pragma unroll
      for (int j = 2; j < 4; j++) bfr[ks][j] = rdB(c, j, ks);
    stA(c, 0, ktp); stA(c, 128, ktp);
    stB(c, 0, 0, ktp); stB(c, 0, 1, ktp);
    __builtin_amdgcn_s_setprio(1);
    mmblk<0, 2>(acc, afr, bfr);
    __builtin_amdgcn_s_setprio(0);
    asm volatile("s_waitcnt vmcnt(12)" ::: "memory");
    __builtin_amdgcn_s_barrier();
    __builtin_amdgcn_sched_barrier(0);
    // ---- phase 2: read A m4-7; stage B(T+2).hi; MFMA q(1,0)
#pragma unroll
    for (int ks = 0; ks < 2; ks++)
#pragma unroll
      for (int j = 0; j < 4; j++) afr[ks][j] = rdA(c, 4 + j, ks);
    stB(c, 1, 0, ktp); stB(c, 1, 1, ktp);
    __builtin_amdgcn_s_setprio(1);
    mmblk<4, 0>(acc, afr, bfr);
    __builtin_amdgcn_s_setprio(0);
    asm volatile("" ::: "memory");
    __builtin_amdgcn_s_barrier();
    __builtin_amdgcn_sched_barrier(0);
    // ---- phase 3: stage A(T+2).q13; MFMA q(1,1)
    stA(c, 64, ktp); stA(c, 192, ktp);
    __builtin_amdgcn_s_setprio(1);
    mmblk<4, 2>(acc, afr, bfr);
    __builtin_amdgcn_s_setprio(0);
    asm volatile("s_waitcnt vmcnt(12)" ::: "memory");
    __builtin_amdgcn_s_barrier();
    __builtin_amdgcn_sched_barrier(0);
    c ^= 1;
  }
  asm volatile("s_waitcnt vmcnt(0)" ::: "memory");

  float* Pz = SPLIT ? ((float*)C + (size_t)blockIdx.z * mn) : nullptr;
#pragma unroll
  for (int mi = 0; mi < 8; mi++) {
#pragma unroll
    for (int r = 0; r < 4; r++) {
      int crow = mt + wm + mi * 16 + lg * 4 + r;
      size_t rb = (size_t)crow * N;
#pragma unroll
      for (int ni = 0; ni < 4; ni++) {
        int col = nt + wn + ni * 16 + l15;
        float v = acc[mi][ni][r];
        if (SPLIT) {
          Pz[rb + col] = v;
        } else {
          if (RESID == 1) v += R[rb + col];
          if (RESID == 2) v += ((const float*)C)[rb + col];
          if (OUTBF) ((u16*)C)[rb + col] = f2bf(v);
          else       ((float*)C)[rb + col] = v;
        }
      }
    }
  }
}

// ---------------- split-K reduce ----------------
template <int RESID, int OUTBF>
__global__ __launch_bounds__(256) void reduce_split(
    const float* __restrict__ part, int nz, size_t mn4,
    void* __restrict__ C, const float* __restrict__ R) {
  const f32x4* p4 = (const f32x4*)part;
  for (size_t i = (size_t)blockIdx.x * 256 + threadIdx.x; i < mn4;
       i += (size_t)gridDim.x * 256) {
    f32x4 s = p4[i];
    for (int z = 1; z < nz; z++) s += p4[(size_t)z * mn4 + i];
    if (RESID == 1) s += ((const f32x4*)R)[i];
    if (RESID == 2) s += ((const f32x4*)C)[i];
    if (OUTBF) {
      u16x4 o; o[0] = f2bf(s[0]); o[1] = f2bf(s[1]); o[2] = f2bf(s[2]); o[3] = f2bf(s[3]);
      ((u16x4*)C)[i] = o;
    } else {
      ((f32x4*)C)[i] = s;
    }
  }
}

// ---------------- QK norm + RoPE + scatter ----------------
__global__ __launch_bounds__(256) void qk_rope(
    const u16* __restrict__ qkv,
    const float* __restrict__ qn0, const float* __restrict__ qn1, const float* __restrict__ qn2,
    const float* __restrict__ kn0, const float* __restrict__ kn1, const float* __restrict__ kn2,
    const int* __restrict__ pos, u16* __restrict__ Q, u16* __restrict__ K) {
  int tk = blockIdx.x;
  int b = tk / 1344, sg = tk % 1344;
  int w = threadIdx.x >> 6, l = threadIdx.x & 63;
  int hr = blockIdx.y * 4 + w;
  int e, off, Se;
  if (sg < 1024)      { e = 0; off = 0;    Se = 1024; }
  else if (sg < 1280) { e = 1; off = 1024; Se = 256;  }
  else                { e = 2; off = 1280; Se = 64;   }
  int r = b * Se + (sg - off);
  size_t rowbase = (e == 0) ? 0 : (e == 1) ? 8388608 : 10485760;
  const u16* src; const float* nw; u16* dst;
  if (hr < 16) {
    src = qkv + rowbase + (size_t)r * 4096 + hr * 128;
    nw = (e == 0) ? qn0 : (e == 1) ? qn1 : qn2;
    dst = Q + ((size_t)(b * 16 + hr) * 1344 + sg) * 128;
  } else {
    int kh = hr - 16;
    src = qkv + rowbase + (size_t)r * 4096 + 2048 + kh * 128;
    nw = (e == 0) ? kn0 : (e == 1) ? kn1 : kn2;
    dst = K + ((size_t)(b * 8 + kh) * 1344 + sg) * 128;
  }
  float x0v = bf2f(src[l]), x1v = bf2f(src[l + 64]);
  float ss = x0v * x0v + x1v * x1v;
#pragma unroll
  for (int m = 1; m < 64; m <<= 1) ss += __shfl_xor(ss, m);
  float rs = rsqrtf(ss * (1.f / 128.f) + 1e-6f);
  float y0 = x0v * rs * nw[l], y1 = x1v * rs * nw[l + 64];
  float p = (float)pos[b * 1344 + sg];
  float inv = exp2f(-(float)l * 0.3114307588956902f);
  float th = p * inv;
  float cz = cosf(th), sz = sinf(th);
  dst[l]      = f2bf(y0 * cz - y1 * sz);
  dst[l + 64] = f2bf(y1 * cz + y0 * sz);
}

// ---------------- V transpose ----------------
__global__ __launch_bounds__(256) void v_trans(const u16* __restrict__ qkv, u16* __restrict__ Vt) {
  __shared__ u16 tile[64][72];
  int st = blockIdx.x;
  int b = st / 21, s0 = (st % 21) * 64;
  int kvh = blockIdx.y >> 1, dh = (blockIdx.y & 1) * 64;
  int t = threadIdx.x;
  int sl = t >> 2, d0 = (t & 3) * 16;
  int sg = s0 + sl;
  int e, off, Se;
  if (sg < 1024)      { e = 0; off = 0;    Se = 1024; }
  else if (sg < 1280) { e = 1; off = 1024; Se = 256;  }
  else                { e = 2; off = 1280; Se = 64;   }
  int r = b * Se + (sg - off);
  size_t rowbase = (e == 0) ? 0 : (e == 1) ? 8388608 : 10485760;
  const u16* src = qkv + rowbase + (size_t)r * 4096 + 3072 + kvh * 128 + dh + d0;
  u16x8 a = *(const u16x8*)src;
  u16x8 bb = *(const u16x8*)(src + 8);
#pragma unroll
  for (int j = 0; j < 8; j++) { tile[sl][d0 + j] = a[j]; tile[sl][d0 + 8 + j] = bb[j]; }
  __syncthreads();
  int dl = t >> 2, sb = (t & 3) * 16;
  u16* dst = Vt + ((size_t)(b * 8 + kvh) * 128 + dh + dl) * 1344 + s0 + sb;
  u16x8 o0, o1;
#pragma unroll
  for (int j = 0; j < 8; j++) { o0[j] = tile[sb + j][dl]; o1[j] = tile[sb + 8 + j][dl]; }
  *(u16x8*)dst = o0;
  *(u16x8*)(dst + 8) = o1;
}

// ---------------- Flash attention ----------------
__global__ __launch_bounds__(256, 2) void attn(
    const u16* __restrict__ Q, const u16* __restrict__ K, const u16* __restrict__ Vt,
    const float* __restrict__ mask, u16* __restrict__ attO) {
  constexpr int S = 1344;
  __shared__ u16 Qs[64 * 128];
  __shared__ u16 Ks[64 * 128];
  __shared__ u16 Vts[128 * 64];
  __shared__ u16 Ps[4][16 * 64];
  int bh = blockIdx.y;
  int b = bh >> 4, h = bh & 15, kvh = h >> 1;
  int q0 = blockIdx.x * 64;
  int t = threadIdx.x, w = t >> 6, l = t & 63;
  const int l15 = l & 15, lg = l >> 4;
  const u16* Qg = Q + ((size_t)(b * 16 + h) * S + q0) * 128;
  const u16* Kg = K + ((size_t)(b * 8 + kvh) * S) * 128;
  const u16* Vg = Vt + ((size_t)(b * 8 + kvh) * 128) * S;

  {
    int unit = t & 15, r16 = t >> 4;
#pragma unroll
    for (int i = 0; i < 4; i++) {
      int row = i * 16 + r16;
      int su = (unit & 8) | ((unit & 7) ^ (row & 7));
      gl_lds16(Qg + (size_t)row * 128 + su * 8, &Qs[row * 128 + unit * 8]);
    }
  }
  __syncthreads();
  s16x8 qf[4];
  {
    int qrow = w * 16 + l15;
#pragma unroll
    for (int ks = 0; ks < 4; ks++) {
      int u = ks * 4 + lg;
      int su = (u & 8) | ((u & 7) ^ (qrow & 7));
      qf[ks] = *(const s16x8*)&Qs[qrow * 128 + su * 8];
    }
  }

  float mrow[4] = {-3e38f, -3e38f, -3e38f, -3e38f};
  float lrow[4] = {0.f, 0.f, 0.f, 0.f};
  f32x4 of[8];
#pragma unroll
  for (int d = 0; d < 8; d++) of[d] = (f32x4){0.f, 0.f, 0.f, 0.f};
  const float scale = 0.08838834764831845f;

  for (int kt = 0; kt < 21; ++kt) {
    int k0 = kt * 64;
    __syncthreads();
    {
      int unit = t & 15, r16 = t >> 4;
#pragma unroll
      for (int i = 0; i < 4; i++) {
        int row = i * 16 + r16;
        int su = (unit & 8) | ((unit & 7) ^ (row & 7));
        gl_lds16(Kg + (size_t)(k0 + row) * 128 + su * 8, &Ks[row * 128 + unit * 8]);
      }
      int u8 = t & 7, r32 = t >> 3;
#pragma unroll
      for (int i = 0; i < 4; i++) {
        int row = i * 32 + r32;
        int su = u8 ^ (row & 7);
        gl_lds16(Vg + (size_t)row * S + k0 + su * 8, &Vts[row * 64 + u8 * 8]);
      }
    }
    __syncthreads();

    f32x4 sf[4];
#pragma unroll
    for (int cb = 0; cb < 4; cb++) {
      f32x4 a = (f32x4){0.f, 0.f, 0.f, 0.f};
      int krow = cb * 16 + l15;
#pragma unroll
      for (int ks = 0; ks < 4; ks++) {
        int u = ks * 4 + lg;
        int su = (u & 8) | ((u & 7) ^ (krow & 7));
        s16x8 kf = *(const s16x8*)&Ks[krow * 128 + su * 8];
        a = mfma16(qf[ks], kf, a);
      }
      sf[cb] = a;
    }

    float pv[4][4], tmax[4];
    int qg0 = q0 + w * 16 + lg * 4;
#pragma unroll
    for (int r = 0; r < 4; r++) {
      const float* mp = mask + ((size_t)(b * S + qg0 + r)) * S + k0 + l15;
      float v0 = sf[0][r] * scale + mp[0];
      float v1 = sf[1][r] * scale + mp[16];
      float v2 = sf[2][r] * scale + mp[32];
      float v3 = sf[3][r] * scale + mp[48];
      pv[0][r] = v0; pv[1][r] = v1; pv[2][r] = v2; pv[3][r] = v3;
      tmax[r] = fmaxf(fmaxf(v0, v1), fmaxf(v2, v3));
    }
#pragma unroll
    for (int m = 1; m < 16; m <<= 1)
#pragma unroll
      for (int r = 0; r < 4; r++) tmax[r] = fmaxf(tmax[r], __shfl_xor(tmax[r], m));

    float fr[4];
#pragma unroll
    for (int r = 0; r < 4; r++) {
      float mnew = fmaxf(mrow[r], tmax[r]);
      fr[r] = __expf(mrow[r] - mnew);
      mrow[r] = mnew;
      float rs = 0.f;
#pragma unroll
      for (int cb = 0; cb < 4; cb++) { pv[cb][r] = __expf(pv[cb][r] - mnew); rs += pv[cb][r]; }
#pragma unroll
      for (int m = 1; m < 16; m <<= 1) rs += __shfl_xor(rs, m);
      lrow[r] = lrow[r] * fr[r] + rs;
    }
#pragma unroll
    for (int d = 0; d < 8; d++)
#pragma unroll
      for (int r = 0; r < 4; r++) of[d][r] *= fr[r];

#pragma unroll
    for (int cb = 0; cb < 4; cb++)
#pragma unroll
      for (int r = 0; r < 4; r++) {
        int prow = lg * 4 + r;
        int col = cb * 16 + l15;
        int su = (col >> 3) ^ (prow & 7);
        Ps[w][prow * 64 + su * 8 + (col & 7)] = f2bf(pv[cb][r]);
      }
    __syncthreads();

    s16x8 pa[2];
#pragma unroll
    for (int ks = 0; ks < 2; ks++) {
      int prow = l15;
      int u = ks * 4 + lg;
      pa[ks] = *(const s16x8*)&Ps[w][prow * 64 + (u ^ (prow & 7)) * 8];
    }
#pragma unroll
    for (int d = 0; d < 8; d++) {
      int vrow = d * 16 + l15;
#pragma unroll
      for (int ks = 0; ks < 2; ks++) {
        int u = ks * 4 + lg;
        s16x8 vf = *(const s16x8*)&Vts[vrow * 64 + (u ^ (vrow & 7)) * 8];
        of[d] = mfma16(pa[ks], vf, of[d]);
      }
    }
  }

#pragma unroll
  for (int r = 0; r < 4; r++) {
    float il = 1.f / lrow[r];
    int sg = q0 + w * 16 + lg * 4 + r;
    u16* orow = attO + ((size_t)(b * S + sg)) * 2048 + h * 128;
#pragma unroll
    for (int d = 0; d < 8; d++) orow[d * 16 + l15] = f2bf(of[d][r] * il);
  }
}

// ---------------- silu(g)*u on fused GU buffer ----------------
__global__ __launch_bounds__(256) void silu_fused(u16* __restrict__ gu, int F8, long total8) {
  long i = (long)blockIdx.x * 256 + threadIdx.x;
  if (i >= total8) return;
  long row = i / F8;
  int c8 = (int)(i - row * F8);
  size_t base = (size_t)row * (F8 * 16) + (size_t)c8 * 8;
  u16x8 gv = *(const u16x8*)(gu + base);
  u16x8 uv = *(const u16x8*)(gu + base + (size_t)F8 * 8);
  u16x8 o;
#pragma unroll
  for (int j = 0; j < 8; j++) {
    float gf = bf2f(gv[j]), uf = bf2f(uv[j]);
    float s = gf / (1.f + __expf(-gf));
    o[j] = f2bf(s * uf);
  }
  *(u16x8*)(gu + base) = o;
}

// ---------------------------------------------------------------------------
extern "C" void kernel_launch(void* const* d_in, const int* in_sizes, int n_in,
                              void* d_out, int out_size, void* d_ws, size_t ws_size,
                              hipStream_t stream) {
  if (ws_size < WS_NEED) return;

  const float* x[3] = {(const float*)d_in[0], (const float*)d_in[1], (const float*)d_in[2]};
  const float* mask = (const float*)d_in[3];
  const int* pos = (const int*)d_in[4];
  auto W = [&](int e, int k) -> const float* { return (const float*)d_in[5 + e * 11 + k]; };

  char* ws = (char*)d_ws;
  u16* wbf  = (u16*)(ws + WB_OFF);
  u16* h1   = (u16*)(ws + H1_OFF);
  u16* h2   = (u16*)(ws + H2_OFF);
  u16* qkv  = (u16*)(ws + QKV_OFF);
  u16* Qb   = (u16*)(ws + QB_OFF);
  u16* Kb   = (u16*)(ws + KB_OFF);
  u16* Vtb  = (u16*)(ws + VT_OFF);
  u16* attO = (u16*)(ws + ATTO_OFF);
  u16* gu   = (u16*)(ws + GU_OFF);
  float* scrA = (float*)(ws + GU_OFF);
  float* scrB = (float*)(ws + QKV_OFF);
  float* scrC = (float*)(ws + H1_OFF);
  float* dout = (float*)d_out;

  const int hid[3] = {2048, 1024, 1024}, ffn[3] = {8192, 4096, 4096};
  const size_t douto[3] = {0, 4194304, 4718592};
  const size_t qkvo[3]  = {0, 8388608, 10485760};
  const size_t guo[3]   = {0, 33554432, 37748736};

  size_t woff[3][7];
  CastTab tab;
  {
    size_t cum = 0; int cc = 0, ci = 0;
    for (int e = 0; e < 3; e++) {
      const int kidx[7] = {2, 3, 4, 5, 8, 9, 10};
      const size_t sz[7] = {(size_t)2048 * hid[e], (size_t)1024 * hid[e], (size_t)1024 * hid[e],
                            (size_t)2048 * hid[e], (size_t)ffn[e] * hid[e],
                            (size_t)ffn[e] * hid[e], (size_t)ffn[e] * hid[e]};
      for (int j = 0; j < 7; j++) {
        woff[e][j] = cum;
        tab.src[ci] = W(e, kidx[j]);
        tab.pre[ci] = cc;
        cum += sz[j];
        cc += (int)(sz[j] >> 15);
        ci++;
      }
    }
    tab.pre[21] = cc;
  }

  auto rgrid = [](size_t mn4) -> unsigned {
    size_t g = (mn4 + 255) >> 8;
    return (unsigned)(g > 2048 ? 2048 : g);
  };

  // 1. weights -> bf16
  cast_weights<<<dim3(3072), dim3(256), 0, stream>>>(tab, wbf);

  // 2. RMSNorm(ln1) -> h1
  for (int e = 0; e < 3; e++)
    rmsnorm_cast<<<dim3(e == 0 ? 2048 : (e == 1 ? 512 : 128)), dim3(256), 0, stream>>>(
        x[e], W(e, 0), h1 + douto[e], hid[e]);

  // 3. fused QKV projections
  // e0: 256^2 8-phase, split-K=2 (grid 256 wg)
  gemm256<0, 0, true><<<dim3(16, 8, 2), dim3(512), 0, stream>>>(
      h1, 2048, 11, 0, 0, wbf + woff[0][0], 2048, 1024, 4096, scrA, nullptr,
      (size_t)8388608);
  reduce_split<0, 1><<<rgrid(2097152), dim3(256), 0, stream>>>(
      scrA, 2, 2097152, qkv, nullptr);
  // e1/e2: 128^2 split-K
  gemm_bt<0, 0, true><<<dim3(32, 4, 2), dim3(256), 0, stream>>>(
      h1 + douto[1], 1024, 9, 0, 0, wbf + woff[1][0], 1024, 512, 4096, scrA, nullptr,
      (size_t)2097152);
  reduce_split<0, 1><<<rgrid(524288), dim3(256), 0, stream>>>(
      scrA, 2, 524288, qkv + qkvo[1], nullptr);
  gemm_bt<0, 0, true><<<dim3(32, 1, 8), dim3(256), 0, stream>>>(
      h1 + douto[2], 1024, 7, 0, 0, wbf + woff[2][0], 1024, 128, 4096, scrA, nullptr,
      (size_t)524288);
  reduce_split<0, 1><<<rgrid(131072), dim3(256), 0, stream>>>(
      scrA, 8, 131072, qkv + qkvo[2], nullptr);

  // 4. q/k norm + rope + scatter; V transpose
  qk_rope<<<dim3(2688, 6), dim3(256), 0, stream>>>(
      qkv, W(0, 6), W(1, 6), W(2, 6), W(0, 7), W(1, 7), W(2, 7), pos, Qb, Kb);
  v_trans<<<dim3(42, 16), dim3(256), 0, stream>>>(qkv, Vtb);

  // 5. attention
  attn<<<dim3(21, 32), dim3(256), 0, stream>>>(Qb, Kb, Vtb, mask, attO);

  // 6. o = att @ wo^T + x -> d_out (f32)
  // e0: 256^2 split-K=4 -> scrA (GU region free until GU GEMMs)
  gemm256<0, 0, true><<<dim3(8, 8, 4), dim3(512), 0, stream>>>(
      attO, 2048, 10, 1344, 0, wbf + woff[0][3], 2048, 512, 2048, scrA, nullptr,
      (size_t)4194304);
  reduce_split<1, 0><<<rgrid(1048576), dim3(256), 0, stream>>>(
      scrA, 4, 1048576, dout, x[0]);
  gemm_bt<0, 0, true><<<dim3(8, 4, 8), dim3(256), 0, stream>>>(
      attO, 2048, 8, 1344, 1024, wbf + woff[1][3], 2048, 256, 1024, scrB, nullptr,
      (size_t)524288);
  reduce_split<1, 0><<<rgrid(131072), dim3(256), 0, stream>>>(
      scrB, 8, 131072, dout + douto[1], x[1]);
  gemm_bt<0, 0, true><<<dim3(8, 1, 16), dim3(256), 0, stream>>>(
      attO, 2048, 6, 1344, 1280, wbf + woff[2][3], 2048, 128, 1024, scrB, nullptr,
      (size_t)131072);
  reduce_split<1, 0><<<rgrid(32768), dim3(256), 0, stream>>>(
      scrB, 16, 32768, dout + douto[2], x[2]);

  // 7. RMSNorm(ln2) -> h2
  for (int e = 0; e < 3; e++)
    rmsnorm_cast<<<dim3(e == 0 ? 2048 : (e == 1 ? 512 : 128)), dim3(256), 0, stream>>>(
        dout + douto[e], W(e, 1), h2 + douto[e], hid[e]);

  // 8. fused g|u projections
  // e0: 256^2 direct (grid 512 wg)
  gemm256<0, 1, false><<<dim3(64, 8), dim3(512), 0, stream>>>(
      h2, 2048, 11, 0, 0, wbf + woff[0][4], 2048, 2048, 16384, gu, nullptr, 0);
  // e1: 128^2 split-K=2 (grid 512 wg)
  gemm_bt<0, 0, true><<<dim3(64, 4, 2), dim3(256), 0, stream>>>(
      h2 + douto[1], 1024, 9, 0, 0, wbf + woff[1][4], 1024, 512, 8192, scrB, nullptr,
      (size_t)4194304);
  reduce_split<0, 1><<<rgrid(1048576), dim3(256), 0, stream>>>(
      scrB, 2, 1048576, gu + guo[1], nullptr);
  // e2: 128^2 split-K=4
  gemm_bt<0, 0, true><<<dim3(64, 1, 4), dim3(256), 0, stream>>>(
      h2 + douto[2], 1024, 7, 0, 0, wbf + woff[2][4], 1024, 256, 8192, scrB, nullptr,
      (size_t)1048576);
  reduce_split<0, 1><<<rgrid(262144), dim3(256), 0, stream>>>(
      scrB, 4, 262144, gu + guo[2], nullptr);

  // 9. m = silu(g)*u
  silu_fused<<<dim3(8192), dim3(256), 0, stream>>>(gu, 1024, 2097152L);
  silu_fused<<<dim3(1024), dim3(256), 0, stream>>>(gu + guo[1], 512, 262144L);
  silu_fused<<<dim3(256), dim3(256), 0, stream>>>(gu + guo[2], 512, 65536L);

  // 10. out += m @ wd^T
  // e0: 256^2 split-K=4 -> scrC (H1..ATTO contiguous dead span, 74 MB)
  gemm256<0, 0, true><<<dim3(8, 8, 4), dim3(512), 0, stream>>>(
      gu, 16384, 11, 0, 0, wbf + woff[0][6], 8192, 2048, 2048, scrC, nullptr,
      (size_t)4194304);
  reduce_split<2, 0><<<rgrid(1048576), dim3(256), 0, stream>>>(
      scrC, 4, 1048576, dout, nullptr);
  gemm_bt<0, 0, true><<<dim3(8, 4, 8), dim3(256), 0, stream>>>(
      gu + guo[1], 8192, 9, 0, 0, wbf + woff[1][6], 4096, 512, 1024, scrB, nullptr,
      (size_t)524288);
  reduce_split<2, 0><<<rgrid(131072), dim3(256), 0, stream>>>(
      scrB, 8, 131072, dout + douto[1], nullptr);
  gemm_bt<0, 0, true><<<dim3(8, 1, 16), dim3(256), 0, stream>>>(
      gu + guo[2], 8192, 7, 0, 0, wbf + woff[2][6], 4096, 256, 1024, scrB, nullptr,
      (size_t)131072);
  reduce_split<2, 0><<<rgrid(32768), dim3(256), 0, stream>>>(
      scrB, 16, 32768, dout + douto[2], nullptr);
}

// Round 5
// 796.075 us; speedup vs baseline: 1.6908x; 1.0167x over previous
//
#include <hip/hip_runtime.h>
#include <cstdint>
#include <cstddef>

// ---------------------------------------------------------------------------
// Qwen3VL-with-experts fused forward, bf16 MFMA. Round 5 (= R4 with link fix):
// gemm256 = two-barrier 8-phase structure (reads/stage -> bar -> lgkm0 ->
// pure MFMA (setprio) -> counted vmcnt -> bar); wg/wu interleaved in the
// weight pool -> silu fused into GEMM epilogue / split reduce.
// ---------------------------------------------------------------------------

using u16 = unsigned short;
typedef __attribute__((ext_vector_type(4))) float  f32x4;
typedef __attribute__((ext_vector_type(4))) u16    u16x4;
typedef __attribute__((ext_vector_type(8))) u16    u16x8;
typedef __attribute__((ext_vector_type(8))) short  s16x8;

__device__ __forceinline__ u16 f2bf(float f) {
  unsigned u = __builtin_bit_cast(unsigned, f);
  u = (u + 0x7FFF + ((u >> 16) & 1)) >> 16;
  return (u16)u;
}
__device__ __forceinline__ float bf2f(u16 h) {
  unsigned u = ((unsigned)h) << 16;
  return __builtin_bit_cast(float, u);
}
__device__ __forceinline__ f32x4 mfma16(s16x8 a, s16x8 b, f32x4 c) {
  return __builtin_amdgcn_mfma_f32_16x16x32_bf16(a, b, c, 0, 0, 0);
}
__device__ __forceinline__ void gl_lds16(const u16* g, u16* l) {
  __builtin_amdgcn_global_load_lds(
      (const __attribute__((address_space(1))) unsigned int*)g,
      (__attribute__((address_space(3))) unsigned int*)l, 16, 0, 0);
}

// ---------------- workspace layout (bytes) ----------------
static constexpr size_t WB_OFF   = 0;                       // bf16 weights 201326592
static constexpr size_t H1_OFF   = WB_OFF   + 201326592;
static constexpr size_t H2_OFF   = H1_OFF   + 9699328;
static constexpr size_t QKV_OFF  = H2_OFF   + 9699328;
static constexpr size_t QB_OFF   = QKV_OFF  + 22020096;
static constexpr size_t KB_OFF   = QB_OFF   + 11010048;
static constexpr size_t VT_OFF   = KB_OFF   + 5505024;
static constexpr size_t ATTO_OFF = VT_OFF   + 5505024;
static constexpr size_t GU_OFF   = ATTO_OFF + 11010048;     // m buffers + scrA
static constexpr size_t WS_NEED  = GU_OFF   + 77594624;     // 353370112
// overlays: scrA=GU_OFF (QKV/WO-e0 partials, before m written)
//           scrB=QKV_OFF (e1/e2 partials after attn)
//           scrC=H1_OFF (WD-e0 partials, 67MB < span H1..GU)

// ---------------- weight cast: 15 plain matrices, one launch ----------------
struct CastTab { const float* src[15]; int pre[16]; };
struct DstoArg { size_t v[15]; };

__global__ __launch_bounds__(256) void cast_weights2(CastTab tab, DstoArg dsto,
                                                     u16* __restrict__ dst) {
  int c = blockIdx.x;
  int a = 0;
  while (c >= tab.pre[a + 1]) a++;
  const f32x4* s = (const f32x4*)(tab.src[a] + ((size_t)(c - tab.pre[a]) << 15));
  u16x4* d = (u16x4*)(dst + dsto.v[a] + (((size_t)(c - tab.pre[a])) << 15));
  int t = threadIdx.x;
  for (int i = t; i < 8192; i += 256) {
    f32x4 v = s[i];
    u16x4 o; o[0] = f2bf(v[0]); o[1] = f2bf(v[1]); o[2] = f2bf(v[2]); o[3] = f2bf(v[3]);
    d[i] = o;
  }
}

// wg/wu -> pool, interleaved in 32-row chunks: pool row 64s+j = wg[32s+j] (j<32),
// pool row 64s+32+j = wu[32s+j].
__global__ __launch_bounds__(256) void cast_gu(
    const float* __restrict__ g, const float* __restrict__ u,
    u16* __restrict__ dst, int logh, long n4) {
  long i = (long)blockIdx.x * 256 + threadIdx.x;
  long stride = (long)gridDim.x * 256;
  int hid = 1 << logh;
  for (; i < n4; i += stride) {
    long e4 = i << 2;
    long r = e4 >> logh;
    int  k = (int)(e4 & (hid - 1));
    long super = r >> 6; int sub = (int)(r & 63);
    const float* src = (sub < 32 ? g + ((super << 5) + sub) * (long)hid
                                 : u + ((super << 5) + (sub - 32)) * (long)hid) + k;
    f32x4 v = *(const f32x4*)src;
    u16x4 o; o[0] = f2bf(v[0]); o[1] = f2bf(v[1]); o[2] = f2bf(v[2]); o[3] = f2bf(v[3]);
    ((u16x4*)dst)[i] = o;
  }
}

// ---------------- RMSNorm (f32 in) -> bf16 out ----------------
__global__ __launch_bounds__(256) void rmsnorm_cast(
    const float* __restrict__ x, const float* __restrict__ w,
    u16* __restrict__ out, int hid) {
  int row = blockIdx.x;
  const f32x4* xr = (const f32x4*)(x + (size_t)row * hid);
  const f32x4* wr = (const f32x4*)w;
  int n4 = hid >> 2;
  int t = threadIdx.x;
  float ss = 0.f;
  for (int i = t; i < n4; i += 256) {
    f32x4 v = xr[i];
    ss += v[0] * v[0] + v[1] * v[1] + v[2] * v[2] + v[3] * v[3];
  }
#pragma unroll
  for (int m = 1; m < 64; m <<= 1) ss += __shfl_xor(ss, m);
  __shared__ float part[4];
  if ((t & 63) == 0) part[t >> 6] = ss;
  __syncthreads();
  float tot = part[0] + part[1] + part[2] + part[3];
  float rs = rsqrtf(tot / (float)hid + 1e-6f);
  u16x4* orow = (u16x4*)(out + (size_t)row * hid);
  for (int i = t; i < n4; i += 256) {
    f32x4 v = xr[i];
    f32x4 g = wr[i];
    u16x4 o;
    o[0] = f2bf(v[0] * rs * g[0]); o[1] = f2bf(v[1] * rs * g[1]);
    o[2] = f2bf(v[2] * rs * g[2]); o[3] = f2bf(v[3] * rs * g[3]);
    orow[i] = o;
  }
}

// ---------------- 128x128 GEMM (m97 structure) for e1/e2 ----------------
template <int RESID, int OUTBF, bool SPLIT>
__global__ __launch_bounds__(256) void gemm_bt(
    const u16* __restrict__ A, int Astride, int logSe, int bstride, int rowoff,
    const u16* __restrict__ Bw, int K, int kLen, int N,
    void* __restrict__ C, const float* __restrict__ R, size_t mn) {
  __shared__ u16 As[128 * 64];
  __shared__ u16 Bs[128 * 64];
  const int t = threadIdx.x;

  int gx = gridDim.x, nwg = gx * gridDim.y;
  int flat = blockIdx.y * gx + blockIdx.x;
  int q = nwg >> 3, r8 = nwg & 7;
  int xcd = flat & 7, idx = flat >> 3;
  int nf = (xcd < r8 ? xcd * (q + 1) : r8 * (q + 1) + (xcd - r8) * q) + idx;
  const int nt = nf % gx, mt = nf / gx;

  const int w = t >> 6, l = t & 63;
  const int wr = (w >> 1) * 64, wc = (w & 1) * 64;
  const int l15 = l & 15, lg = l >> 4;
  f32x4 acc[4][4];
#pragma unroll
  for (int i = 0; i < 4; i++)
#pragma unroll
    for (int j = 0; j < 4; j++) acc[i][j] = (f32x4){0.f, 0.f, 0.f, 0.f};

  const int sr = t >> 3, su0 = t & 7;
  const int mask_se = (1 << logSe) - 1;
  const int k0 = SPLIT ? (int)blockIdx.z * kLen : 0;
  const int k1 = k0 + kLen;

  for (int kt = k0; kt < k1; kt += 64) {
    __syncthreads();
#pragma unroll
    for (int i = 0; i < 4; i++) {
      int row = i * 32 + sr;
      int gr = mt * 128 + row;
      int grow = ((gr >> logSe) * bstride) + (gr & mask_se) + rowoff;
      int su = su0 ^ (row & 7);
      gl_lds16(A + (size_t)grow * Astride + kt + su * 8, &As[row * 64 + su0 * 8]);
    }
#pragma unroll
    for (int i = 0; i < 4; i++) {
      int row = i * 32 + sr;
      int gc = nt * 128 + row;
      int su = su0 ^ (row & 7);
      gl_lds16(Bw + (size_t)gc * K + kt + su * 8, &Bs[row * 64 + su0 * 8]);
    }
    __syncthreads();

    s16x8 af[2][4], bfr[2][4];
#pragma unroll
    for (int mi = 0; mi < 4; mi++) {
      int row = wr + mi * 16 + l15;
#pragma unroll
      for (int ks = 0; ks < 2; ks++) {
        int u = ks * 4 + lg;
        af[ks][mi] = *(const s16x8*)&As[row * 64 + (u ^ (row & 7)) * 8];
      }
    }
#pragma unroll
    for (int ni = 0; ni < 4; ni++) {
      int row = wc + ni * 16 + l15;
#pragma unroll
      for (int ks = 0; ks < 2; ks++) {
        int u = ks * 4 + lg;
        bfr[ks][ni] = *(const s16x8*)&Bs[row * 64 + (u ^ (row & 7)) * 8];
      }
    }
#pragma unroll
    for (int ks = 0; ks < 2; ks++)
#pragma unroll
      for (int mi = 0; mi < 4; mi++)
#pragma unroll
        for (int ni = 0; ni < 4; ni++)
          acc[mi][ni] = mfma16(af[ks][mi], bfr[ks][ni], acc[mi][ni]);
  }

  float* Pz = SPLIT ? ((float*)C + (size_t)blockIdx.z * mn) : nullptr;
#pragma unroll
  for (int mi = 0; mi < 4; mi++) {
#pragma unroll
    for (int r = 0; r < 4; r++) {
      int crow = mt * 128 + wr + mi * 16 + lg * 4 + r;
      size_t rb = (size_t)crow * N;
#pragma unroll
      for (int ni = 0; ni < 4; ni++) {
        int col = nt * 128 + wc + ni * 16 + l15;
        float v = acc[mi][ni][r];
        if (SPLIT) {
          Pz[rb + col] = v;
        } else {
          if (RESID == 1) v += R[rb + col];
          if (RESID == 2) v += ((const float*)C)[rb + col];
          if (OUTBF) ((u16*)C)[rb + col] = f2bf(v);
          else       ((float*)C)[rb + col] = v;
        }
      }
    }
  }
}

// ---------------- 256x256 two-barrier 8-phase GEMM for e0 ----------------
template <int MB, int N0>
__device__ __forceinline__ void mmblk(f32x4 (&acc)[8][4], const s16x8 (&afr)[2][4],
                                      const s16x8 (&bfr)[2][4]) {
#pragma unroll
  for (int ks = 0; ks < 2; ks++)
#pragma unroll
    for (int j = 0; j < 4; j++)
#pragma unroll
      for (int ni = 0; ni < 2; ni++)
        acc[MB + j][N0 + ni] =
            mfma16(afr[ks][j], bfr[ks][N0 + ni], acc[MB + j][N0 + ni]);
}

#define GB256_BAR() do { __builtin_amdgcn_sched_barrier(0); \
                         __builtin_amdgcn_s_barrier(); } while (0)
#define GB256_LGKM0() do { asm volatile("s_waitcnt lgkmcnt(0)" ::: "memory"); \
                           __builtin_amdgcn_sched_barrier(0); } while (0)

// SILU: non-split only, decode interleaved g/u pairs, write bf16 m, row stride N/2.
template <int RESID, int OUTBF, bool SPLIT, bool SILU>
__global__ __launch_bounds__(512, 2) void gemm256(
    const u16* __restrict__ A, int Astride, int logSe, int bstride, int rowoff,
    const u16* __restrict__ Bw, int K, int kLen, int N,
    void* __restrict__ C, const float* __restrict__ R, size_t mn) {
  __shared__ u16 As[2][256 * 64];
  __shared__ u16 Bs[2][256 * 64];
  const int t = threadIdx.x;

  int gx = gridDim.x, nwg = gx * gridDim.y;
  int flat = blockIdx.y * gx + blockIdx.x;
  int q = nwg >> 3, r8 = nwg & 7;
  int xcd = flat & 7, idx = flat >> 3;
  int nf = (xcd < r8 ? xcd * (q + 1) : r8 * (q + 1) + (xcd - r8) * q) + idx;
  const int nt = (nf % gx) * 256, mt = (nf / gx) * 256;

  const int w = t >> 6, l = t & 63;
  const int wm = (w >> 2) * 128, wn = (w & 3) * 64;
  const int l15 = l & 15, lg = l >> 4;
  const int sr8 = t >> 3, u8 = t & 7;
  const int mask_se = (1 << logSe) - 1;
  const int k0 = SPLIT ? (int)blockIdx.z * kLen : 0;
  const int kLast = k0 + kLen - 64;

  f32x4 acc[8][4];
#pragma unroll
  for (int i = 0; i < 8; i++)
#pragma unroll
    for (int j = 0; j < 4; j++) acc[i][j] = (f32x4){0.f, 0.f, 0.f, 0.f};

  auto stA = [&](int c, int qb, int ktv) {
    int row = qb + sr8;
    int gr = mt + row;
    int grow = ((gr >> logSe) * bstride) + (gr & mask_se) + rowoff;
    int su = u8 ^ (row & 7);
    gl_lds16(A + (size_t)grow * Astride + ktv + su * 8, &As[c][row * 64 + u8 * 8]);
  };
  auto stB = [&](int c, int half, int pair, int ktv) {
    int row = (pair * 2 + (t >> 8)) * 64 + half * 32 + ((t & 255) >> 3);
    int su = u8 ^ (row & 7);
    gl_lds16(Bw + (size_t)(nt + row) * K + ktv + su * 8, &Bs[c][row * 64 + u8 * 8]);
  };
  auto rdA = [&](int c, int mi, int ks) -> s16x8 {
    int row = wm + mi * 16 + l15;
    int u = ks * 4 + lg;
    return *(const s16x8*)&As[c][row * 64 + (u ^ (row & 7)) * 8];
  };
  auto rdB = [&](int c, int ni, int ks) -> s16x8 {
    int row = wn + ni * 16 + l15;
    int u = ks * 4 + lg;
    return *(const s16x8*)&Bs[c][row * 64 + (u ^ (row & 7)) * 8];
  };

  // prologue: stage tiles 0 (buf0) and 1 (buf1) in steady-state issue order
  {
    int kt1 = k0 + 64;
    stA(0, 0, k0); stA(0, 128, k0);
    stB(0, 0, 0, k0); stB(0, 0, 1, k0);
    stB(0, 1, 0, k0); stB(0, 1, 1, k0);
    stA(0, 64, k0); stA(0, 192, k0);
    stA(1, 0, kt1); stA(1, 128, kt1);
    stB(1, 0, 0, kt1); stB(1, 0, 1, kt1);
    stB(1, 1, 0, kt1); stB(1, 1, 1, kt1);
    stA(1, 64, kt1); stA(1, 192, kt1);
  }
  asm volatile("s_waitcnt vmcnt(12)" ::: "memory");
  GB256_BAR();

  s16x8 afr[2][4], bfr[2][4];
  int c = 0;
  for (int kt0 = k0; kt0 < k0 + kLen; kt0 += 64) {
    int ktp = kt0 + 128 <= kLast ? kt0 + 128 : kLast;  // tile T+2 (clamped)
    // ---- phase 0: rd A m0-3 + B n0-1 | bar | lgkm0 | MFMA q(0,0) | vm(10) bar
#pragma unroll
    for (int ks = 0; ks < 2; ks++) {
#pragma unroll
      for (int j = 0; j < 4; j++) afr[ks][j] = rdA(c, j, ks);
#pragma unroll
      for (int j = 0; j < 2; j++) bfr[ks][j] = rdB(c, j, ks);
    }
    GB256_BAR();
    GB256_LGKM0();
    __builtin_amdgcn_s_setprio(1);
    mmblk<0, 0>(acc, afr, bfr);
    __builtin_amdgcn_s_setprio(0);
    asm volatile("s_waitcnt vmcnt(10)" ::: "memory");
    GB256_BAR();
    // ---- phase 1: rd B n2-3; stage A.q02+B.lo(T+2) | bar | lgkm0 | q(0,1) | vm(12) bar
#pragma unroll
    for (int ks = 0; ks < 2; ks++)
#pragma unroll
      for (int j = 2; j < 4; j++) bfr[ks][j] = rdB(c, j, ks);
    stA(c, 0, ktp); stA(c, 128, ktp);
    stB(c, 0, 0, ktp); stB(c, 0, 1, ktp);
    GB256_BAR();
    GB256_LGKM0();
    __builtin_amdgcn_s_setprio(1);
    mmblk<0, 2>(acc, afr, bfr);
    __builtin_amdgcn_s_setprio(0);
    asm volatile("s_waitcnt vmcnt(12)" ::: "memory");
    GB256_BAR();
    // ---- phase 2: rd A m4-7; stage B.hi(T+2) | bar | lgkm0 | q(1,0) | bar
#pragma unroll
    for (int ks = 0; ks < 2; ks++)
#pragma unroll
      for (int j = 0; j < 4; j++) afr[ks][j] = rdA(c, 4 + j, ks);
    stB(c, 1, 0, ktp); stB(c, 1, 1, ktp);
    GB256_BAR();
    GB256_LGKM0();
    __builtin_amdgcn_s_setprio(1);
    mmblk<4, 0>(acc, afr, bfr);
    __builtin_amdgcn_s_setprio(0);
    GB256_BAR();
    // ---- phase 3: stage A.q13(T+2); MFMA q(1,1) (pure reg) | vm(12) bar
    stA(c, 64, ktp); stA(c, 192, ktp);
    __builtin_amdgcn_s_setprio(1);
    mmblk<4, 2>(acc, afr, bfr);
    __builtin_amdgcn_s_setprio(0);
    asm volatile("s_waitcnt vmcnt(12)" ::: "memory");
    GB256_BAR();
    c ^= 1;
  }
  asm volatile("s_waitcnt vmcnt(0)" ::: "memory");

  float* Pz = SPLIT ? ((float*)C + (size_t)blockIdx.z * mn) : nullptr;
#pragma unroll
  for (int mi = 0; mi < 8; mi++) {
#pragma unroll
    for (int r = 0; r < 4; r++) {
      int crow = mt + wm + mi * 16 + lg * 4 + r;
      if (SILU) {
        // cols (nt+wn)..(nt+wn+63) = one 64-col super-chunk: 32 g + 32 u
        size_t rb = (size_t)crow * (N >> 1);
        int super = (nt + wn) >> 6;
#pragma unroll
        for (int ni = 0; ni < 2; ni++) {
          int col = super * 32 + ni * 16 + l15;
          float g = acc[mi][ni][r], u = acc[mi][ni + 2][r];
          float s = g / (1.f + __expf(-g));
          ((u16*)C)[rb + col] = f2bf(s * u);
        }
      } else {
        size_t rb = (size_t)crow * N;
#pragma unroll
        for (int ni = 0; ni < 4; ni++) {
          int col = nt + wn + ni * 16 + l15;
          float v = acc[mi][ni][r];
          if (SPLIT) {
            Pz[rb + col] = v;
          } else {
            if (RESID == 1) v += R[rb + col];
            if (RESID == 2) v += ((const float*)C)[rb + col];
            if (OUTBF) ((u16*)C)[rb + col] = f2bf(v);
            else       ((float*)C)[rb + col] = v;
          }
        }
      }
    }
  }
}

// ---------------- split-K reduce ----------------
template <int RESID, int OUTBF>
__global__ __launch_bounds__(256) void reduce_split(
    const float* __restrict__ part, int nz, size_t mn4,
    void* __restrict__ C, const float* __restrict__ R) {
  const f32x4* p4 = (const f32x4*)part;
  for (size_t i = (size_t)blockIdx.x * 256 + threadIdx.x; i < mn4;
       i += (size_t)gridDim.x * 256) {
    f32x4 s = p4[i];
    for (int z = 1; z < nz; z++) s += p4[(size_t)z * mn4 + i];
    if (RESID == 1) s += ((const f32x4*)R)[i];
    if (RESID == 2) s += ((const f32x4*)C)[i];
    if (OUTBF) {
      u16x4 o; o[0] = f2bf(s[0]); o[1] = f2bf(s[1]); o[2] = f2bf(s[2]); o[3] = f2bf(s[3]);
      ((u16x4*)C)[i] = o;
    } else {
      ((f32x4*)C)[i] = s;
    }
  }
}

// split-K reduce + silu on interleaved g/u partials (cols: 64s+j = g, 64s+32+j = u)
__global__ __launch_bounds__(256) void reduce_silu(
    const float* __restrict__ part, int nz, size_t mnF4, int F4, size_t mnPart,
    u16* __restrict__ mout) {
  for (size_t i = (size_t)blockIdx.x * 256 + threadIdx.x; i < mnF4;
       i += (size_t)gridDim.x * 256) {
    size_t row = i / F4;
    int cm4 = (int)(i - row * F4) * 4;
    int super = cm4 >> 5, j = cm4 & 31;
    size_t gb = row * (size_t)(F4 * 8) + (size_t)super * 64 + j;
    f32x4 g = *(const f32x4*)(part + gb);
    f32x4 u = *(const f32x4*)(part + gb + 32);
    for (int z = 1; z < nz; z++) {
      g += *(const f32x4*)(part + (size_t)z * mnPart + gb);
      u += *(const f32x4*)(part + (size_t)z * mnPart + gb + 32);
    }
    u16x4 o;
#pragma unroll
    for (int k = 0; k < 4; k++) {
      float s = g[k] / (1.f + __expf(-g[k]));
      o[k] = f2bf(s * u[k]);
    }
    *(u16x4*)(mout + row * (size_t)(F4 * 4) + cm4) = o;
  }
}

// ---------------- QK norm + RoPE + scatter ----------------
__global__ __launch_bounds__(256) void qk_rope(
    const u16* __restrict__ qkv,
    const float* __restrict__ qn0, const float* __restrict__ qn1, const float* __restrict__ qn2,
    const float* __restrict__ kn0, const float* __restrict__ kn1, const float* __restrict__ kn2,
    const int* __restrict__ pos, u16* __restrict__ Q, u16* __restrict__ K) {
  int tk = blockIdx.x;
  int b = tk / 1344, sg = tk % 1344;
  int w = threadIdx.x >> 6, l = threadIdx.x & 63;
  int hr = blockIdx.y * 4 + w;
  int e, off, Se;
  if (sg < 1024)      { e = 0; off = 0;    Se = 1024; }
  else if (sg < 1280) { e = 1; off = 1024; Se = 256;  }
  else                { e = 2; off = 1280; Se = 64;   }
  int r = b * Se + (sg - off);
  size_t rowbase = (e == 0) ? 0 : (e == 1) ? 8388608 : 10485760;
  const u16* src; const float* nw; u16* dst;
  if (hr < 16) {
    src = qkv + rowbase + (size_t)r * 4096 + hr * 128;
    nw = (e == 0) ? qn0 : (e == 1) ? qn1 : qn2;
    dst = Q + ((size_t)(b * 16 + hr) * 1344 + sg) * 128;
  } else {
    int kh = hr - 16;
    src = qkv + rowbase + (size_t)r * 4096 + 2048 + kh * 128;
    nw = (e == 0) ? kn0 : (e == 1) ? kn1 : kn2;
    dst = K + ((size_t)(b * 8 + kh) * 1344 + sg) * 128;
  }
  float x0v = bf2f(src[l]), x1v = bf2f(src[l + 64]);
  float ss = x0v * x0v + x1v * x1v;
#pragma unroll
  for (int m = 1; m < 64; m <<= 1) ss += __shfl_xor(ss, m);
  float rs = rsqrtf(ss * (1.f / 128.f) + 1e-6f);
  float y0 = x0v * rs * nw[l], y1 = x1v * rs * nw[l + 64];
  float p = (float)pos[b * 1344 + sg];
  float inv = exp2f(-(float)l * 0.3114307588956902f);
  float th = p * inv;
  float cz = cosf(th), sz = sinf(th);
  dst[l]      = f2bf(y0 * cz - y1 * sz);
  dst[l + 64] = f2bf(y1 * cz + y0 * sz);
}

// ---------------- V transpose ----------------
__global__ __launch_bounds__(256) void v_trans(const u16* __restrict__ qkv, u16* __restrict__ Vt) {
  __shared__ u16 tile[64][72];
  int st = blockIdx.x;
  int b = st / 21, s0 = (st % 21) * 64;
  int kvh = blockIdx.y >> 1, dh = (blockIdx.y & 1) * 64;
  int t = threadIdx.x;
  int sl = t >> 2, d0 = (t & 3) * 16;
  int sg = s0 + sl;
  int e, off, Se;
  if (sg < 1024)      { e = 0; off = 0;    Se = 1024; }
  else if (sg < 1280) { e = 1; off = 1024; Se = 256;  }
  else                { e = 2; off = 1280; Se = 64;   }
  int r = b * Se + (sg - off);
  size_t rowbase = (e == 0) ? 0 : (e == 1) ? 8388608 : 10485760;
  const u16* src = qkv + rowbase + (size_t)r * 4096 + 3072 + kvh * 128 + dh + d0;
  u16x8 a = *(const u16x8*)src;
  u16x8 bb = *(const u16x8*)(src + 8);
#pragma unroll
  for (int j = 0; j < 8; j++) { tile[sl][d0 + j] = a[j]; tile[sl][d0 + 8 + j] = bb[j]; }
  __syncthreads();
  int dl = t >> 2, sb = (t & 3) * 16;
  u16* dst = Vt + ((size_t)(b * 8 + kvh) * 128 + dh + dl) * 1344 + s0 + sb;
  u16x8 o0, o1;
#pragma unroll
  for (int j = 0; j < 8; j++) { o0[j] = tile[sb + j][dl]; o1[j] = tile[sb + 8 + j][dl]; }
  *(u16x8*)dst = o0;
  *(u16x8*)(dst + 8) = o1;
}

// ---------------- Flash attention ----------------
__global__ __launch_bounds__(256, 2) void attn(
    const u16* __restrict__ Q, const u16* __restrict__ K, const u16* __restrict__ Vt,
    const float* __restrict__ mask, u16* __restrict__ attO) {
  constexpr int S = 1344;
  __shared__ u16 Qs[64 * 128];
  __shared__ u16 Ks[64 * 128];
  __shared__ u16 Vts[128 * 64];
  __shared__ u16 Ps[4][16 * 64];
  int bh = blockIdx.y;
  int b = bh >> 4, h = bh & 15, kvh = h >> 1;
  int q0 = blockIdx.x * 64;
  int t = threadIdx.x, w = t >> 6, l = t & 63;
  const int l15 = l & 15, lg = l >> 4;
  const u16* Qg = Q + ((size_t)(b * 16 + h) * S + q0) * 128;
  const u16* Kg = K + ((size_t)(b * 8 + kvh) * S) * 128;
  const u16* Vg = Vt + ((size_t)(b * 8 + kvh) * 128) * S;

  {
    int unit = t & 15, r16 = t >> 4;
#pragma unroll
    for (int i = 0; i < 4; i++) {
      int row = i * 16 + r16;
      int su = (unit & 8) | ((unit & 7) ^ (row & 7));
      gl_lds16(Qg + (size_t)row * 128 + su * 8, &Qs[row * 128 + unit * 8]);
    }
  }
  __syncthreads();
  s16x8 qf[4];
  {
    int qrow = w * 16 + l15;
#pragma unroll
    for (int ks = 0; ks < 4; ks++) {
      int u = ks * 4 + lg;
      int su = (u & 8) | ((u & 7) ^ (qrow & 7));
      qf[ks] = *(const s16x8*)&Qs[qrow * 128 + su * 8];
    }
  }

  float mrow[4] = {-3e38f, -3e38f, -3e38f, -3e38f};
  float lrow[4] = {0.f, 0.f, 0.f, 0.f};
  f32x4 of[8];
#pragma unroll
  for (int d = 0; d < 8; d++) of[d] = (f32x4){0.f, 0.f, 0.f, 0.f};
  const float scale = 0.08838834764831845f;

  for (int kt = 0; kt < 21; ++kt) {
    int k0 = kt * 64;
    __syncthreads();
    {
      int unit = t & 15, r16 = t >> 4;
#pragma unroll
      for (int i = 0; i < 4; i++) {
        int row = i * 16 + r16;
        int su = (unit & 8) | ((unit & 7) ^ (row & 7));
        gl_lds16(Kg + (size_t)(k0 + row) * 128 + su * 8, &Ks[row * 128 + unit * 8]);
      }
      int u8 = t & 7, r32 = t >> 3;
#pragma unroll
      for (int i = 0; i < 4; i++) {
        int row = i * 32 + r32;
        int su = u8 ^ (row & 7);
        gl_lds16(Vg + (size_t)row * S + k0 + su * 8, &Vts[row * 64 + u8 * 8]);
      }
    }
    __syncthreads();

    f32x4 sf[4];
#pragma unroll
    for (int cb = 0; cb < 4; cb++) {
      f32x4 a = (f32x4){0.f, 0.f, 0.f, 0.f};
      int krow = cb * 16 + l15;
#pragma unroll
      for (int ks = 0; ks < 4; ks++) {
        int u = ks * 4 + lg;
        int su = (u & 8) | ((u & 7) ^ (krow & 7));
        s16x8 kf = *(const s16x8*)&Ks[krow * 128 + su * 8];
        a = mfma16(qf[ks], kf, a);
      }
      sf[cb] = a;
    }

    float pv[4][4], tmax[4];
    int qg0 = q0 + w * 16 + lg * 4;
#pragma unroll
    for (int r = 0; r < 4; r++) {
      const float* mp = mask + ((size_t)(b * S + qg0 + r)) * S + k0 + l15;
      float v0 = sf[0][r] * scale + mp[0];
      float v1 = sf[1][r] * scale + mp[16];
      float v2 = sf[2][r] * scale + mp[32];
      float v3 = sf[3][r] * scale + mp[48];
      pv[0][r] = v0; pv[1][r] = v1; pv[2][r] = v2; pv[3][r] = v3;
      tmax[r] = fmaxf(fmaxf(v0, v1), fmaxf(v2, v3));
    }
#pragma unroll
    for (int m = 1; m < 16; m <<= 1)
#pragma unroll
      for (int r = 0; r < 4; r++) tmax[r] = fmaxf(tmax[r], __shfl_xor(tmax[r], m));

    float fr[4];
#pragma unroll
    for (int r = 0; r < 4; r++) {
      float mnew = fmaxf(mrow[r], tmax[r]);
      fr[r] = __expf(mrow[r] - mnew);
      mrow[r] = mnew;
      float rs = 0.f;
#pragma unroll
      for (int cb = 0; cb < 4; cb++) { pv[cb][r] = __expf(pv[cb][r] - mnew); rs += pv[cb][r]; }
#pragma unroll
      for (int m = 1; m < 16; m <<= 1) rs += __shfl_xor(rs, m);
      lrow[r] = lrow[r] * fr[r] + rs;
    }
#pragma unroll
    for (int d = 0; d < 8; d++)
#pragma unroll
      for (int r = 0; r < 4; r++) of[d][r] *= fr[r];

#pragma unroll
    for (int cb = 0; cb < 4; cb++)
#pragma unroll
      for (int r = 0; r < 4; r++) {
        int prow = lg * 4 + r;
        int col = cb * 16 + l15;
        int su = (col >> 3) ^ (prow & 7);
        Ps[w][prow * 64 + su * 8 + (col & 7)] = f2bf(pv[cb][r]);
      }
    __syncthreads();

    s16x8 pa[2];
#pragma unroll
    for (int ks = 0; ks < 2; ks++) {
      int prow = l15;
      int u = ks * 4 + lg;
      pa[ks] = *(const s16x8*)&Ps[w][prow * 64 + (u ^ (prow & 7)) * 8];
    }
#pragma unroll
    for (int d = 0; d < 8; d++) {
      int vrow = d * 16 + l15;
#pragma unroll
      for (int ks = 0; ks < 2; ks++) {
        int u = ks * 4 + lg;
        s16x8 vf = *(const s16x8*)&Vts[vrow * 64 + (u ^ (vrow & 7)) * 8];
        of[d] = mfma16(pa[ks], vf, of[d]);
      }
    }
  }

#pragma unroll
  for (int r = 0; r < 4; r++) {
    float il = 1.f / lrow[r];
    int sg = q0 + w * 16 + lg * 4 + r;
    u16* orow = attO + ((size_t)(b * S + sg)) * 2048 + h * 128;
#pragma unroll
    for (int d = 0; d < 8; d++) orow[d * 16 + l15] = f2bf(of[d][r] * il);
  }
}

// ---------------------------------------------------------------------------
extern "C" void kernel_launch(void* const* d_in, const int* in_sizes, int n_in,
                              void* d_out, int out_size, void* d_ws, size_t ws_size,
                              hipStream_t stream) {
  if (ws_size < WS_NEED) return;

  const float* x[3] = {(const float*)d_in[0], (const float*)d_in[1], (const float*)d_in[2]};
  const float* mask = (const float*)d_in[3];
  const int* pos = (const int*)d_in[4];
  auto W = [&](int e, int k) -> const float* { return (const float*)d_in[5 + e * 11 + k]; };

  char* ws = (char*)d_ws;
  u16* wbf  = (u16*)(ws + WB_OFF);
  u16* h1   = (u16*)(ws + H1_OFF);
  u16* h2   = (u16*)(ws + H2_OFF);
  u16* qkv  = (u16*)(ws + QKV_OFF);
  u16* Qb   = (u16*)(ws + QB_OFF);
  u16* Kb   = (u16*)(ws + KB_OFF);
  u16* Vtb  = (u16*)(ws + VT_OFF);
  u16* attO = (u16*)(ws + ATTO_OFF);
  u16* m    = (u16*)(ws + GU_OFF);
  float* scrA = (float*)(ws + GU_OFF);
  float* scrB = (float*)(ws + QKV_OFF);
  float* scrC = (float*)(ws + H1_OFF);
  float* dout = (float*)d_out;

  const int hid[3] = {2048, 1024, 1024}, ffn[3] = {8192, 4096, 4096};
  const size_t douto[3] = {0, 4194304, 4718592};
  const size_t qkvo[3]  = {0, 8388608, 10485760};
  const size_t mo[3]    = {0, 16777216, 18874368};

  // pool layout per expert: wq,wk,wv,wo,[wg|wu interleaved],wd
  size_t woff[3][7];
  CastTab tab;
  DstoArg dsarg;
  {
    size_t cum = 0; int cc = 0, ci = 0;
    for (int e = 0; e < 3; e++) {
      const size_t sz[7] = {(size_t)2048 * hid[e], (size_t)1024 * hid[e], (size_t)1024 * hid[e],
                            (size_t)2048 * hid[e], (size_t)ffn[e] * hid[e],
                            (size_t)ffn[e] * hid[e], (size_t)ffn[e] * hid[e]};
      const int kidx[7] = {2, 3, 4, 5, 8, 9, 10};
      for (int j = 0; j < 7; j++) {
        woff[e][j] = cum;
        if (j != 4 && j != 5) {
          tab.src[ci] = W(e, kidx[j]);
          tab.pre[ci] = cc;
          dsarg.v[ci] = cum;
          cc += (int)(sz[j] >> 15);
          ci++;
        }
        cum += sz[j];
      }
    }
    tab.pre[15] = cc;  // 1536 chunks
  }

  auto rgrid = [](size_t mn4) -> unsigned {
    size_t g = (mn4 + 255) >> 8;
    return (unsigned)(g > 2048 ? 2048 : g);
  };

  // 1. weights -> bf16 (plain + interleaved gu)
  cast_weights2<<<dim3(1536), dim3(256), 0, stream>>>(tab, dsarg, wbf);
  cast_gu<<<dim3(2048), dim3(256), 0, stream>>>(
      W(0, 8), W(0, 9), wbf + woff[0][4], 11, 8388608L);
  cast_gu<<<dim3(1024), dim3(256), 0, stream>>>(
      W(1, 8), W(1, 9), wbf + woff[1][4], 10, 2097152L);
  cast_gu<<<dim3(1024), dim3(256), 0, stream>>>(
      W(2, 8), W(2, 9), wbf + woff[2][4], 10, 2097152L);

  // 2. RMSNorm(ln1) -> h1
  for (int e = 0; e < 3; e++)
    rmsnorm_cast<<<dim3(e == 0 ? 2048 : (e == 1 ? 512 : 128)), dim3(256), 0, stream>>>(
        x[e], W(e, 0), h1 + douto[e], hid[e]);

  // 3. fused QKV projections
  gemm256<0, 0, true, false><<<dim3(16, 8, 2), dim3(512), 0, stream>>>(
      h1, 2048, 11, 0, 0, wbf + woff[0][0], 2048, 1024, 4096, scrA, nullptr,
      (size_t)8388608);
  reduce_split<0, 1><<<rgrid(2097152), dim3(256), 0, stream>>>(
      scrA, 2, 2097152, qkv, nullptr);
  gemm_bt<0, 0, true><<<dim3(32, 4, 2), dim3(256), 0, stream>>>(
      h1 + douto[1], 1024, 9, 0, 0, wbf + woff[1][0], 1024, 512, 4096, scrA, nullptr,
      (size_t)2097152);
  reduce_split<0, 1><<<rgrid(524288), dim3(256), 0, stream>>>(
      scrA, 2, 524288, qkv + qkvo[1], nullptr);
  gemm_bt<0, 0, true><<<dim3(32, 1, 8), dim3(256), 0, stream>>>(
      h1 + douto[2], 1024, 7, 0, 0, wbf + woff[2][0], 1024, 128, 4096, scrA, nullptr,
      (size_t)524288);
  reduce_split<0, 1><<<rgrid(131072), dim3(256), 0, stream>>>(
      scrA, 8, 131072, qkv + qkvo[2], nullptr);

  // 4. rope + v transpose
  qk_rope<<<dim3(2688, 6), dim3(256), 0, stream>>>(
      qkv, W(0, 6), W(1, 6), W(2, 6), W(0, 7), W(1, 7), W(2, 7), pos, Qb, Kb);
  v_trans<<<dim3(42, 16), dim3(256), 0, stream>>>(qkv, Vtb);

  // 5. attention
  attn<<<dim3(21, 32), dim3(256), 0, stream>>>(Qb, Kb, Vtb, mask, attO);

  // 6. o = att @ wo^T + x -> d_out (f32)
  gemm256<0, 0, true, false><<<dim3(8, 8, 4), dim3(512), 0, stream>>>(
      attO, 2048, 10, 1344, 0, wbf + woff[0][3], 2048, 512, 2048, scrA, nullptr,
      (size_t)4194304);
  reduce_split<1, 0><<<rgrid(1048576), dim3(256), 0, stream>>>(
      scrA, 4, 1048576, dout, x[0]);
  gemm_bt<0, 0, true><<<dim3(8, 4, 8), dim3(256), 0, stream>>>(
      attO, 2048, 8, 1344, 1024, wbf + woff[1][3], 2048, 256, 1024, scrB, nullptr,
      (size_t)524288);
  reduce_split<1, 0><<<rgrid(131072), dim3(256), 0, stream>>>(
      scrB, 8, 131072, dout + douto[1], x[1]);
  gemm_bt<0, 0, true><<<dim3(8, 1, 16), dim3(256), 0, stream>>>(
      attO, 2048, 6, 1344, 1280, wbf + woff[2][3], 2048, 128, 1024, scrB, nullptr,
      (size_t)131072);
  reduce_split<1, 0><<<rgrid(32768), dim3(256), 0, stream>>>(
      scrB, 16, 32768, dout + douto[2], x[2]);

  // 7. RMSNorm(ln2) -> h2
  for (int e = 0; e < 3; e++)
    rmsnorm_cast<<<dim3(e == 0 ? 2048 : (e == 1 ? 512 : 128)), dim3(256), 0, stream>>>(
        dout + douto[e], W(e, 1), h2 + douto[e], hid[e]);

  // 8. g|u projections with fused silu -> m
  gemm256<0, 0, false, true><<<dim3(64, 8), dim3(512), 0, stream>>>(
      h2, 2048, 11, 0, 0, wbf + woff[0][4], 2048, 2048, 16384, m, nullptr, 0);
  gemm_bt<0, 0, true><<<dim3(64, 4, 2), dim3(256), 0, stream>>>(
      h2 + douto[1], 1024, 9, 0, 0, wbf + woff[1][4], 1024, 512, 8192, scrB, nullptr,
      (size_t)4194304);
  reduce_silu<<<rgrid(524288), dim3(256), 0, stream>>>(
      scrB, 2, 524288, 1024, 4194304, m + mo[1]);
  gemm_bt<0, 0, true><<<dim3(64, 1, 4), dim3(256), 0, stream>>>(
      h2 + douto[2], 1024, 7, 0, 0, wbf + woff[2][4], 1024, 256, 8192, scrB, nullptr,
      (size_t)1048576);
  reduce_silu<<<rgrid(131072), dim3(256), 0, stream>>>(
      scrB, 4, 131072, 1024, 1048576, m + mo[2]);

  // 9. out += m @ wd^T
  gemm256<0, 0, true, false><<<dim3(8, 8, 4), dim3(512), 0, stream>>>(
      m, 8192, 11, 0, 0, wbf + woff[0][6], 8192, 2048, 2048, scrC, nullptr,
      (size_t)4194304);
  reduce_split<2, 0><<<rgrid(1048576), dim3(256), 0, stream>>>(
      scrC, 4, 1048576, dout, nullptr);
  gemm_bt<0, 0, true><<<dim3(8, 4, 8), dim3(256), 0, stream>>>(
      m + mo[1], 4096, 9, 0, 0, wbf + woff[1][6], 4096, 512, 1024, scrB, nullptr,
      (size_t)524288);
  reduce_split<2, 0><<<rgrid(131072), dim3(256), 0, stream>>>(
      scrB, 8, 131072, dout + douto[1], nullptr);
  gemm_bt<0, 0, true><<<dim3(8, 1, 16), dim3(256), 0, stream>>>(
      m + mo[2], 4096, 7, 0, 0, wbf + woff[2][6], 4096, 256, 1024, scrB, nullptr,
      (size_t)131072);
  reduce_split<2, 0><<<rgrid(32768), dim3(256), 0, stream>>>(
      scrB, 16, 32768, dout + douto[2], nullptr);
}